// Round 10
// baseline (637.998 us; speedup 1.0000x reference)
//
#include <hip/hip_runtime.h>
#include <hip/hip_bf16.h>
#include <math.h>

#define NN 50000
#define EE 800000
#define NT (EE / 16)          // 50000 flat 16-edge tiles (exact)
#define NTN (NN / 16)         // 3125 node tiles

// edge_mfma64: 1536 blocks = exactly 6/CU (LDS cap); balanced wave partition
#define NBLK64 1536
#define NW64 (NBLK64 * 4)     // 6144 waves
#define B64 (NT / NW64)       // 8
#define R64 (NT % NW64)       // 848

// edge_mfma16: small LDS -> 8 blocks/CU
#define NBLK16 2048
#define NW16 (NBLK16 * 4)     // 8192 waves
#define B16 (NT / NW16)       // 6
#define R16 (NT % NW16)       // 848

#define NBF 782               // bn/cvt kernels: 1 node tile per wave
#define NWF (NBF * 4)         // 3128 waves >= 3125

typedef short s8v __attribute__((ext_vector_type(8)));   // 8 x bf16 (4 VGPRs)
typedef float f4v __attribute__((ext_vector_type(4)));   // MFMA C/D

__device__ __forceinline__ short f2bf(float f) {         // fp32 -> bf16 RNE
    unsigned u = __float_as_uint(f);
    u += 0x7fffu + ((u >> 16) & 1u);
    return (short)(u >> 16);
}

// monotone fp32 <-> uint encode for atomicMax-based segment max.
// key 0 (memset) < enc(any float) -> "never touched" -> decodes to 0.
__device__ __forceinline__ unsigned enc(float f) {
    unsigned u = __float_as_uint(f);
    return (u & 0x80000000u) ? ~u : (u | 0x80000000u);
}
__device__ __forceinline__ float dec(unsigned k) {
    if (k == 0u) return 0.0f;                            // empty segment -> 0
    unsigned u = (k & 0x80000000u) ? (k & 0x7fffffffu) : ~k;
    return __uint_as_float(u);
}

// mish(x) = x * (e^{2x}+2e^x) / (e^{2x}+2e^x+2); guard large x
__device__ __forceinline__ float mish_fast(float v) {
    float t = __expf(v);
    float s = t * (t + 2.0f);
    float r = v * s * __builtin_amdgcn_rcpf(s + 2.0f);
    return (v > 15.0f) ? v : r;
}

#define MFMA16(a, b, c) __builtin_amdgcn_mfma_f32_16x16x32_bf16(a, b, c, 0, 0, 0)

// ---------------- CSR build (dst-sorted edge list) ----------------

__global__ __launch_bounds__(256) void count_k(const int* __restrict__ ei,
                                               int* __restrict__ cnt) {
    int e = blockIdx.x * 256 + threadIdx.x;
    if (e < EE) atomicAdd(&cnt[ei[EE + e]], 1);   // row 1 = dst
}

#define NBS 196                                    // ceil(NN/256)

__global__ __launch_bounds__(256) void scan_part(const int* __restrict__ cnt,
                                                 int* __restrict__ part) {
    int t = threadIdx.x, i = blockIdx.x * 256 + t;
    __shared__ int ps[256];
    ps[t] = (i < NN) ? cnt[i] : 0;
    __syncthreads();
    for (int off = 128; off > 0; off >>= 1) {
        if (t < off) ps[t] += ps[t + off];
        __syncthreads();
    }
    if (t == 0) part[blockIdx.x] = ps[0];
}

__global__ __launch_bounds__(256) void scan_top(int* __restrict__ part) {
    int t = threadIdx.x;
    int v = (t < NBS) ? part[t] : 0;
    __shared__ int ps[256];
    ps[t] = v;
    __syncthreads();
    for (int off = 1; off < 256; off <<= 1) {
        int u = (t >= off) ? ps[t - off] : 0;
        __syncthreads();
        ps[t] += u;
        __syncthreads();
    }
    if (t < NBS) part[t] = ps[t] - v;              // exclusive
}

__global__ __launch_bounds__(256) void scan_fin(const int* __restrict__ cnt,
                                                const int* __restrict__ part,
                                                int* __restrict__ row_off,
                                                int* __restrict__ cur) {
    int t = threadIdx.x, i = blockIdx.x * 256 + t;
    int v = (i < NN) ? cnt[i] : 0;
    __shared__ int ps[256];
    ps[t] = v;
    __syncthreads();
    for (int off = 1; off < 256; off <<= 1) {
        int u = (t >= off) ? ps[t - off] : 0;
        __syncthreads();
        ps[t] += u;
        __syncthreads();
    }
    int excl = ps[t] - v + part[blockIdx.x];
    if (i < NN) {
        row_off[i] = excl;
        cur[i] = excl;
        if (i == NN - 1) row_off[NN] = excl + v;
    }
}

__global__ __launch_bounds__(256) void scatter_k(const int* __restrict__ ei,
                                                 int* __restrict__ cur,
                                                 int* __restrict__ csr_src,
                                                 int* __restrict__ csr_dst) {
    int e = blockIdx.x * 256 + threadIdx.x;
    if (e < EE) {
        int d = ei[EE + e];
        int p = atomicAdd(&cur[d], 1);
        csr_src[p] = ei[e];
        csr_dst[p] = d;
    }
}

// -------- layer-0 fused: fp32->bf16 convert + a0 GEMM + zero y/y8 --------
// a0 output transposed within a row: a0[n*64 + i*4 + nb] holds ch nb*16+i.

__global__ __launch_bounds__(256)
void cvt_a0(const float* __restrict__ x, const float* __restrict__ w1,
            const float* __restrict__ b1, unsigned short* __restrict__ xb,
            float* __restrict__ a0, unsigned* __restrict__ y,
            unsigned* __restrict__ y8) {
    const int tid = threadIdx.x;
    const int lane = tid & 63;
    const int wid = blockIdx.x * 4 + (tid >> 6);
    const int i = lane & 15, q = lane >> 4;
    s8v wf[4][2];
#pragma unroll
    for (int nb = 0; nb < 4; nb++)
#pragma unroll
        for (int kh = 0; kh < 2; kh++)
#pragma unroll
            for (int j = 0; j < 8; j++) {
                int k = kh * 32 + q * 8 + j, n = nb * 16 + i;
                wf[nb][kh][j] = f2bf(w1[k * 64 + n] - w1[(64 + k) * 64 + n]);
            }
    float bia[4];
#pragma unroll
    for (int nb = 0; nb < 4; nb++) bia[nb] = b1[nb * 16 + i];

    for (int t = wid; t < NTN; t += NWF) {
        const int row = t * 16 + i;
        const float* xr = x + (size_t)row * 64 + q * 8;
        f4v x0 = *(const f4v*)xr,        x1 = *(const f4v*)(xr + 4);
        f4v x2 = *(const f4v*)(xr + 32), x3 = *(const f4v*)(xr + 36);
        s8v af0, af1;
#pragma unroll
        for (int j = 0; j < 4; j++) {
            af0[j] = f2bf(x0[j]); af0[4 + j] = f2bf(x1[j]);
            af1[j] = f2bf(x2[j]); af1[4 + j] = f2bf(x3[j]);
        }
        unsigned short* xw = xb + (size_t)row * 64 + q * 8;
        *(s8v*)xw = af0;
        *(s8v*)(xw + 32) = af1;
        const int rowq = t * 16 + q * 4;
#pragma unroll
        for (int nb = 0; nb < 4; nb++) {
            f4v c = {0.f, 0.f, 0.f, 0.f};
            c = MFMA16(af0, wf[nb][0], c);
            c = MFMA16(af1, wf[nb][1], c);
#pragma unroll
            for (int r = 0; r < 4; r++)
                a0[(size_t)(rowq + r) * 64 + i * 4 + nb] = c[r] + bia[nb];
        }
    }
    // zero the atomic-max accumulators (replaces two memset dispatches)
    const int gt = blockIdx.x * 256 + tid, gs = NBF * 256;
    for (int idx = gt; idx < NN * 64; idx += gs) y[idx] = 0u;
    for (int idx = gt; idx < NN * 8; idx += gs) y8[idx] = 0u;
}

// -------- fused BN apply + bf16 emit + NEXT layer's a0 GEMM + y re-zero ----

__global__ __launch_bounds__(256)
void bn_a0_64(unsigned* __restrict__ yk, const float* __restrict__ st,
              const float* __restrict__ g, const float* __restrict__ be,
              const float* __restrict__ w1n, const float* __restrict__ b1n,
              unsigned short* __restrict__ xbout, float* __restrict__ a0out) {
    __shared__ float sa[64], sb[64];
    const int tid = threadIdx.x;
    if (tid < 64) {
        float mu  = st[tid] * (1.0f / NN);
        float var = st[64 + tid] * (1.0f / NN) - mu * mu;
        float sc  = rsqrtf(var + 1e-5f) * g[tid];
        sa[tid] = sc;
        sb[tid] = be[tid] - mu * sc;
    }
    __syncthreads();
    const int lane = tid & 63;
    const int wid = blockIdx.x * 4 + (tid >> 6);
    const int i = lane & 15, q = lane >> 4;

    s8v wf[4][2];
#pragma unroll
    for (int nb = 0; nb < 4; nb++)
#pragma unroll
        for (int kh = 0; kh < 2; kh++)
#pragma unroll
            for (int j = 0; j < 8; j++) {
                int k = kh * 32 + q * 8 + j, n = nb * 16 + i;
                wf[nb][kh][j] = f2bf(w1n[k * 64 + n] - w1n[(64 + k) * 64 + n]);
            }
    float bia[4];
#pragma unroll
    for (int nb = 0; nb < 4; nb++) bia[nb] = b1n[nb * 16 + i];

    // per-lane norm constants for its 16 channels (k = kh*32 + q*8 + j)
    f4v a00 = *(const f4v*)(sa + q * 8),      a01 = *(const f4v*)(sa + q * 8 + 4);
    f4v a10 = *(const f4v*)(sa + 32 + q * 8), a11 = *(const f4v*)(sa + 36 + q * 8);
    f4v b00 = *(const f4v*)(sb + q * 8),      b01 = *(const f4v*)(sb + q * 8 + 4);
    f4v b10 = *(const f4v*)(sb + 32 + q * 8), b11 = *(const f4v*)(sb + 36 + q * 8);

    const uint4 z4 = {0u, 0u, 0u, 0u};
    for (int t = wid; t < NTN; t += NWF) {
        const int row = t * 16 + i;
        unsigned* yr = yk + (size_t)row * 64 + q * 8;
        uint4 u0 = *(const uint4*)yr,        u1 = *(const uint4*)(yr + 4);
        uint4 u2 = *(const uint4*)(yr + 32), u3 = *(const uint4*)(yr + 36);
        s8v af0, af1;
        af0[0] = f2bf(dec(u0.x) * a00[0] + b00[0]);
        af0[1] = f2bf(dec(u0.y) * a00[1] + b00[1]);
        af0[2] = f2bf(dec(u0.z) * a00[2] + b00[2]);
        af0[3] = f2bf(dec(u0.w) * a00[3] + b00[3]);
        af0[4] = f2bf(dec(u1.x) * a01[0] + b01[0]);
        af0[5] = f2bf(dec(u1.y) * a01[1] + b01[1]);
        af0[6] = f2bf(dec(u1.z) * a01[2] + b01[2]);
        af0[7] = f2bf(dec(u1.w) * a01[3] + b01[3]);
        af1[0] = f2bf(dec(u2.x) * a10[0] + b10[0]);
        af1[1] = f2bf(dec(u2.y) * a10[1] + b10[1]);
        af1[2] = f2bf(dec(u2.z) * a10[2] + b10[2]);
        af1[3] = f2bf(dec(u2.w) * a10[3] + b10[3]);
        af1[4] = f2bf(dec(u3.x) * a11[0] + b11[0]);
        af1[5] = f2bf(dec(u3.y) * a11[1] + b11[1]);
        af1[6] = f2bf(dec(u3.z) * a11[2] + b11[2]);
        af1[7] = f2bf(dec(u3.w) * a11[3] + b11[3]);

        unsigned short* xw = xbout + (size_t)row * 64 + q * 8;
        *(s8v*)xw = af0;
        *(s8v*)(xw + 32) = af1;
        *(uint4*)yr = z4;        *(uint4*)(yr + 4) = z4;    // re-zero for next layer
        *(uint4*)(yr + 32) = z4; *(uint4*)(yr + 36) = z4;

        const int rowq = t * 16 + q * 4;
#pragma unroll
        for (int nb = 0; nb < 4; nb++) {
            f4v c = {0.f, 0.f, 0.f, 0.f};
            c = MFMA16(af0, wf[nb][0], c);
            c = MFMA16(af1, wf[nb][1], c);
#pragma unroll
            for (int r = 0; r < 4; r++)
                a0out[(size_t)(rowq + r) * 64 + i * 4 + nb] = c[r] + bia[nb];
        }
    }
}

// variant for layer 2 -> 3: next layer dout = 8

__global__ __launch_bounds__(256)
void bn_a0_8(unsigned* __restrict__ yk, const float* __restrict__ st,
             const float* __restrict__ g, const float* __restrict__ be,
             const float* __restrict__ w1n, const float* __restrict__ b1n,
             unsigned short* __restrict__ xbout, float* __restrict__ a08) {
    __shared__ float sa[64], sb[64];
    const int tid = threadIdx.x;
    if (tid < 64) {
        float mu  = st[tid] * (1.0f / NN);
        float var = st[64 + tid] * (1.0f / NN) - mu * mu;
        float sc  = rsqrtf(var + 1e-5f) * g[tid];
        sa[tid] = sc;
        sb[tid] = be[tid] - mu * sc;
    }
    __syncthreads();
    const int lane = tid & 63;
    const int wid = blockIdx.x * 4 + (tid >> 6);
    const int i = lane & 15, q = lane >> 4;

    s8v wf[2];
#pragma unroll
    for (int kh = 0; kh < 2; kh++)
#pragma unroll
        for (int j = 0; j < 8; j++) {
            int k = kh * 32 + q * 8 + j;
            wf[kh][j] = (i < 8) ? f2bf(w1n[k * 8 + i] - w1n[(64 + k) * 8 + i]) : (short)0;
        }
    const float bia = (i < 8) ? b1n[i] : 0.0f;

    f4v a00 = *(const f4v*)(sa + q * 8),      a01 = *(const f4v*)(sa + q * 8 + 4);
    f4v a10 = *(const f4v*)(sa + 32 + q * 8), a11 = *(const f4v*)(sa + 36 + q * 8);
    f4v b00 = *(const f4v*)(sb + q * 8),      b01 = *(const f4v*)(sb + q * 8 + 4);
    f4v b10 = *(const f4v*)(sb + 32 + q * 8), b11 = *(const f4v*)(sb + 36 + q * 8);

    for (int t = wid; t < NTN; t += NWF) {
        const int row = t * 16 + i;
        const unsigned* yr = yk + (size_t)row * 64 + q * 8;
        uint4 u0 = *(const uint4*)yr,        u1 = *(const uint4*)(yr + 4);
        uint4 u2 = *(const uint4*)(yr + 32), u3 = *(const uint4*)(yr + 36);
        s8v af0, af1;
        af0[0] = f2bf(dec(u0.x) * a00[0] + b00[0]);
        af0[1] = f2bf(dec(u0.y) * a00[1] + b00[1]);
        af0[2] = f2bf(dec(u0.z) * a00[2] + b00[2]);
        af0[3] = f2bf(dec(u0.w) * a00[3] + b00[3]);
        af0[4] = f2bf(dec(u1.x) * a01[0] + b01[0]);
        af0[5] = f2bf(dec(u1.y) * a01[1] + b01[1]);
        af0[6] = f2bf(dec(u1.z) * a01[2] + b01[2]);
        af0[7] = f2bf(dec(u1.w) * a01[3] + b01[3]);
        af1[0] = f2bf(dec(u2.x) * a10[0] + b10[0]);
        af1[1] = f2bf(dec(u2.y) * a10[1] + b10[1]);
        af1[2] = f2bf(dec(u2.z) * a10[2] + b10[2]);
        af1[3] = f2bf(dec(u2.w) * a10[3] + b10[3]);
        af1[4] = f2bf(dec(u3.x) * a11[0] + b11[0]);
        af1[5] = f2bf(dec(u3.y) * a11[1] + b11[1]);
        af1[6] = f2bf(dec(u3.z) * a11[2] + b11[2]);
        af1[7] = f2bf(dec(u3.w) * a11[3] + b11[3]);

        unsigned short* xw = xbout + (size_t)row * 64 + q * 8;
        *(s8v*)xw = af0;
        *(s8v*)(xw + 32) = af1;

        f4v c = {0.f, 0.f, 0.f, 0.f};
        c = MFMA16(af0, wf[0], c);
        c = MFMA16(af1, wf[1], c);
        if (i < 8) {
            const int rowq = t * 16 + q * 4;
#pragma unroll
            for (int r = 0; r < 4; r++)
                a08[(size_t)(rowq + r) * 8 + i] = c[r] + bia;
        }
    }
}

// ------- edge-major fused MLP + segmented max, dout=64 -------
// (inner loop identical to R8/R9; balanced wave partition over 1536 blocks)

__global__ __launch_bounds__(256)
void edge_mfma64(const unsigned short* __restrict__ xb, const float* __restrict__ a0,
                 const float* __restrict__ w1, const float* __restrict__ w2,
                 const float* __restrict__ b2,
                 const int* __restrict__ csr_src, const int* __restrict__ csr_dst,
                 unsigned* __restrict__ y) {
    __shared__ float uld[4][16 * 68];                 // per-wave tile, stride 68
    __shared__ int dseg[4][2][20];                    // per-wave dst ids, dbuf
    __shared__ short w2l[8 * 64 * 8];                 // W2 frags: (nb*2+kh, lane, j)
    const int lane = threadIdx.x & 63;
    const int wv = threadIdx.x >> 6;
    const int wid = blockIdx.x * 4 + wv;
    const int i = lane & 15, q = lane >> 4;
    float* up = &uld[wv][0];

    // W1bot fragments stay register-resident (32 VGPRs)
    s8v w1f[4][2];
#pragma unroll
    for (int nb = 0; nb < 4; nb++)
#pragma unroll
        for (int kh = 0; kh < 2; kh++)
#pragma unroll
            for (int j = 0; j < 8; j++) {
                int k = kh * 32 + q * 8 + j, n = nb * 16 + i;
                w1f[nb][kh][j] = f2bf(w1[(64 + k) * 64 + n]);
            }
    // stage this wave's nb(=wv) W2 fragments into shared LDS
    {
        const int nb = wv;
#pragma unroll
        for (int kh = 0; kh < 2; kh++) {
            s8v uu;
#pragma unroll
            for (int j = 0; j < 8; j++) {
                int k = kh * 32 + q * 8 + j;
                uu[j] = f2bf(w2[k * 64 + nb * 16 + i]);
            }
            *(s8v*)(w2l + ((nb * 2 + kh) * 64 + lane) * 8) = uu;
        }
    }
    __syncthreads();

    const float b2c = b2[lane];                       // channel = lane (scan)

    // balanced partition: first R64 waves get B64+1 tiles, rest B64
    int t = wid * B64 + (wid < R64 ? wid : R64);
    const int tend = t + B64 + (wid < R64 ? 1 : 0);

    s8v af0_c, af1_c;
    {
        int s0 = csr_src[t * 16 + i];
        const unsigned short* xr = xb + (size_t)s0 * 64;
        af0_c = *(const s8v*)(xr + q * 8);
        af1_c = *(const s8v*)(xr + 32 + q * 8);
    }
    int src_n = (t + 1 < tend) ? csr_src[(t + 1) * 16 + i] : 0;
    if (lane < 17) {
        int e = t * 16 + lane;
        dseg[wv][t & 1][lane] = (e < EE) ? csr_dst[e] : -1;
    }
    asm volatile("s_waitcnt lgkmcnt(0)" ::: "memory");
    int dq_c[4];
#pragma unroll
    for (int r = 0; r < 4; r++) dq_c[r] = dseg[wv][t & 1][q * 4 + r];
    f4v a0r_c[4];
#pragma unroll
    for (int r = 0; r < 4; r++)
        a0r_c[r] = *(const f4v*)(a0 + (size_t)dq_c[r] * 64 + i * 4);

    float run = -INFINITY;                            // per-channel running max

    for (; t < tend; t++) {
        const bool has_n = (t + 1) < tend;
        int* dsg = &dseg[wv][t & 1][0];
        int* dsg_n = &dseg[wv][(t + 1) & 1][0];

        if (has_n && lane < 17) {
            int e = (t + 1) * 16 + lane;
            dsg_n[lane] = (e < EE) ? csr_dst[e] : -1;
        }
        s8v af0_n = {0,0,0,0,0,0,0,0}, af1_n = {0,0,0,0,0,0,0,0};
        if (has_n) {
            const unsigned short* xr = xb + (size_t)src_n * 64;
            af0_n = *(const s8v*)(xr + q * 8);
            af1_n = *(const s8v*)(xr + 32 + q * 8);
        }
        int src_nn = (t + 2 < tend) ? csr_src[(t + 2) * 16 + i] : 0;

        // GEMM1
        f4v c0 = {0.f, 0.f, 0.f, 0.f}, c1 = c0, c2 = c0, c3 = c0;
        c0 = MFMA16(af0_c, w1f[0][0], c0); c0 = MFMA16(af1_c, w1f[0][1], c0);
        c1 = MFMA16(af0_c, w1f[1][0], c1); c1 = MFMA16(af1_c, w1f[1][1], c1);
        c2 = MFMA16(af0_c, w1f[2][0], c2); c2 = MFMA16(af1_c, w1f[2][1], c2);
        c3 = MFMA16(af0_c, w1f[3][0], c3); c3 = MFMA16(af1_c, w1f[3][1], c3);

        asm volatile("" ::: "memory");
#pragma unroll
        for (int r = 0; r < 4; r++) {
            const int ro = (q * 4 + r) * 68 + i;
            up[ro +  0] = mish_fast(c0[r] + a0r_c[r][0]);
            up[ro + 16] = mish_fast(c1[r] + a0r_c[r][1]);
            up[ro + 32] = mish_fast(c2[r] + a0r_c[r][2]);
            up[ro + 48] = mish_fast(c3[r] + a0r_c[r][3]);
        }
        asm volatile("s_waitcnt lgkmcnt(0)" ::: "memory");   // wait#2

        int dq_n[4];
        f4v a0r_n[4];
        if (has_n) {
#pragma unroll
            for (int r = 0; r < 4; r++) dq_n[r] = dsg_n[q * 4 + r];
#pragma unroll
            for (int r = 0; r < 4; r++)
                a0r_n[r] = *(const f4v*)(a0 + (size_t)dq_n[r] * 64 + i * 4);
        }

        s8v uf[2];
#pragma unroll
        for (int kh = 0; kh < 2; kh++) {
            const f4v* rp = (const f4v*)(up + i * 68 + kh * 32 + q * 8);
            f4v v0 = rp[0], v1 = rp[1];
            s8v uu;
            uu[0] = f2bf(v0[0]); uu[1] = f2bf(v0[1]);
            uu[2] = f2bf(v0[2]); uu[3] = f2bf(v0[3]);
            uu[4] = f2bf(v1[0]); uu[5] = f2bf(v1[1]);
            uu[6] = f2bf(v1[2]); uu[7] = f2bf(v1[3]);
            uf[kh] = uu;
        }
        asm volatile("" ::: "memory");

        // GEMM2 (B fragments streamed from shared LDS)
        f4v cc[4];
#pragma unroll
        for (int nb = 0; nb < 4; nb++) {
            s8v b0 = *(const s8v*)(w2l + ((nb * 2 + 0) * 64 + lane) * 8);
            s8v b1v = *(const s8v*)(w2l + ((nb * 2 + 1) * 64 + lane) * 8);
            f4v c = {0.f, 0.f, 0.f, 0.f};
            c = MFMA16(uf[0], b0, c);
            c = MFMA16(uf[1], b1v, c);
            cc[nb] = c;
        }

#pragma unroll
        for (int nb = 0; nb < 4; nb++)
#pragma unroll
            for (int r = 0; r < 4; r++)
                up[(q * 4 + r) * 68 + nb * 16 + i] = cc[nb][r];
        asm volatile("s_waitcnt lgkmcnt(0)" ::: "memory");   // wait#3

        float v[16];
#pragma unroll
        for (int row = 0; row < 16; row++) v[row] = up[row * 68 + lane];

        int dcur = dsg[0];
#pragma unroll
        for (int row = 0; row < 16; row++) {
            run = fmaxf(run, v[row]);
            int dn = (row < 15) ? dsg[row + 1] : (has_n ? dsg[16] : -1);
            if (dcur != dn) {
                atomicMax(&y[(size_t)dcur * 64 + lane], enc(run + b2c));
                run = -INFINITY;
            }
            dcur = dn;
        }
        asm volatile("s_waitcnt lgkmcnt(0)" ::: "memory");  // WAR guard

        src_n = src_nn;
        af0_c = af0_n; af1_c = af1_n;
#pragma unroll
        for (int r = 0; r < 4; r++) a0r_c[r] = a0r_n[r];
    }
}

// ------- edge-major final layer, dout=8; balanced partition over 2048 blocks -

__global__ __launch_bounds__(256)
void edge_mfma16(const unsigned short* __restrict__ xb, const float* __restrict__ a0,
                 const float* __restrict__ w1, const float* __restrict__ w2,
                 const float* __restrict__ b2,
                 const int* __restrict__ csr_src, const int* __restrict__ csr_dst,
                 unsigned* __restrict__ y8) {
    __shared__ float uld[4][16 * 20];
    __shared__ int dseg[4][2][20];
    const int lane = threadIdx.x & 63;
    const int wv = threadIdx.x >> 6;
    const int wid = blockIdx.x * 4 + wv;
    const int i = lane & 15, q = lane >> 4;
    float* up = &uld[wv][0];

    s8v w1f[2], w2f;
#pragma unroll
    for (int kh = 0; kh < 2; kh++)
#pragma unroll
        for (int j = 0; j < 8; j++) {
            int k = kh * 32 + q * 8 + j;
            w1f[kh][j] = (i < 8) ? f2bf(w1[(64 + k) * 8 + i]) : (short)0;
        }
#pragma unroll
    for (int j = 0; j < 8; j++)
        w2f[j] = (q == 0 && i < 8) ? f2bf(w2[j * 8 + i]) : (short)0;
    const float b2c = (lane < 8) ? b2[lane] : 0.0f;

    int t = wid * B16 + (wid < R16 ? wid : R16);
    const int tend = t + B16 + (wid < R16 ? 1 : 0);

    s8v af0_c, af1_c;
    {
        int s0 = csr_src[t * 16 + i];
        const unsigned short* xr = xb + (size_t)s0 * 64;
        af0_c = *(const s8v*)(xr + q * 8);
        af1_c = *(const s8v*)(xr + 32 + q * 8);
    }
    int src_n = (t + 1 < tend) ? csr_src[(t + 1) * 16 + i] : 0;
    if (lane < 17) {
        int e = t * 16 + lane;
        dseg[wv][t & 1][lane] = (e < EE) ? csr_dst[e] : -1;
    }
    asm volatile("s_waitcnt lgkmcnt(0)" ::: "memory");
    int dq_c[4];
#pragma unroll
    for (int r = 0; r < 4; r++) dq_c[r] = dseg[wv][t & 1][q * 4 + r];
    float av_c[4];
#pragma unroll
    for (int r = 0; r < 4; r++)
        av_c[r] = (i < 8) ? a0[(size_t)dq_c[r] * 8 + i] : 0.0f;

    float run = -INFINITY;

    for (; t < tend; t++) {
        const bool has_n = (t + 1) < tend;
        int* dsg = &dseg[wv][t & 1][0];
        int* dsg_n = &dseg[wv][(t + 1) & 1][0];

        if (has_n && lane < 17) {
            int e = (t + 1) * 16 + lane;
            dsg_n[lane] = (e < EE) ? csr_dst[e] : -1;
        }
        s8v af0_n = {0,0,0,0,0,0,0,0}, af1_n = {0,0,0,0,0,0,0,0};
        if (has_n) {
            const unsigned short* xr = xb + (size_t)src_n * 64;
            af0_n = *(const s8v*)(xr + q * 8);
            af1_n = *(const s8v*)(xr + 32 + q * 8);
        }
        int src_nn = (t + 2 < tend) ? csr_src[(t + 2) * 16 + i] : 0;

        f4v c = {0.f, 0.f, 0.f, 0.f};
        c = MFMA16(af0_c, w1f[0], c);
        c = MFMA16(af1_c, w1f[1], c);

        asm volatile("" ::: "memory");
#pragma unroll
        for (int r = 0; r < 4; r++)
            up[(q * 4 + r) * 20 + i] = mish_fast(c[r] + av_c[r]);   // cols 8..15 = 0
        asm volatile("s_waitcnt lgkmcnt(0)" ::: "memory");           // wait#2

        int dq_n[4];
        float av_n[4] = {0, 0, 0, 0};
        if (has_n) {
#pragma unroll
            for (int r = 0; r < 4; r++) dq_n[r] = dsg_n[q * 4 + r];
#pragma unroll
            for (int r = 0; r < 4; r++)
                av_n[r] = (i < 8) ? a0[(size_t)dq_n[r] * 8 + i] : 0.0f;
        }

        s8v uf = {0,0,0,0,0,0,0,0};
        if (q < 2) {                                   // k = q*8+j < 16
            const f4v* rp = (const f4v*)(up + i * 20 + q * 8);
            f4v v0 = rp[0], v1 = rp[1];
            uf[0] = f2bf(v0[0]); uf[1] = f2bf(v0[1]);
            uf[2] = f2bf(v0[2]); uf[3] = f2bf(v0[3]);
            uf[4] = f2bf(v1[0]); uf[5] = f2bf(v1[1]);
            uf[6] = f2bf(v1[2]); uf[7] = f2bf(v1[3]);
        }
        asm volatile("" ::: "memory");

        f4v cc = {0.f, 0.f, 0.f, 0.f};
        cc = MFMA16(uf, w2f, cc);

#pragma unroll
        for (int r = 0; r < 4; r++)
            up[(q * 4 + r) * 20 + i] = cc[r];
        asm volatile("s_waitcnt lgkmcnt(0)" ::: "memory");           // wait#3

        float v[16];
#pragma unroll
        for (int row = 0; row < 16; row++) v[row] = up[row * 20 + (lane & 7)];

        int dcur = dsg[0];
#pragma unroll
        for (int row = 0; row < 16; row++) {
            run = fmaxf(run, v[row]);
            int dn = (row < 15) ? dsg[row + 1] : (has_n ? dsg[16] : -1);
            if (dcur != dn) {
                if (lane < 8)
                    atomicMax(&y8[(size_t)dcur * 8 + lane], enc(run + b2c));
                run = -INFINITY;
            }
            dcur = dn;
        }
        asm volatile("s_waitcnt lgkmcnt(0)" ::: "memory");

        src_n = src_nn;
        af0_c = af0_n; af1_c = af1_n;
#pragma unroll
        for (int r = 0; r < 4; r++) av_c[r] = av_n[r];
    }
}

// ---------------- BatchNorm stats (vectorized: uint4 per thread) ------------

__global__ __launch_bounds__(256)
void bn_stats(const unsigned* __restrict__ yk, float* __restrict__ st) {
    const int tid = threadIdx.x;
    const int c4 = (tid & 15) * 4;                 // 4-channel group
    const int r = tid >> 4;                        // row slot (0..15)
    f4v s = {0.f, 0.f, 0.f, 0.f}, qq = s;
    for (int n = blockIdx.x * 16 + r; n < NN; n += gridDim.x * 16) {
        uint4 u = *(const uint4*)(yk + (size_t)n * 64 + c4);
        float v0 = dec(u.x), v1 = dec(u.y), v2 = dec(u.z), v3 = dec(u.w);
        s[0] += v0; s[1] += v1; s[2] += v2; s[3] += v3;
        qq[0] = fmaf(v0, v0, qq[0]); qq[1] = fmaf(v1, v1, qq[1]);
        qq[2] = fmaf(v2, v2, qq[2]); qq[3] = fmaf(v3, v3, qq[3]);
    }
    __shared__ float ls[1024], lq[1024];
    *(f4v*)(ls + tid * 4) = s;
    *(f4v*)(lq + tid * 4) = qq;
    __syncthreads();
    for (int off = 128; off >= 16; off >>= 1) {
        if (tid < off) {
            f4v a = *(f4v*)(ls + tid * 4), b = *(f4v*)(ls + (tid + off) * 4);
            f4v c = *(f4v*)(lq + tid * 4), d = *(f4v*)(lq + (tid + off) * 4);
            *(f4v*)(ls + tid * 4) = a + b;
            *(f4v*)(lq + tid * 4) = c + d;
        }
        __syncthreads();
    }
    if (tid < 16) {
        f4v a = *(f4v*)(ls + tid * 4), c = *(f4v*)(lq + tid * 4);
#pragma unroll
        for (int k = 0; k < 4; k++) {
            atomicAdd(&st[tid * 4 + k], a[k]);
            atomicAdd(&st[64 + tid * 4 + k], c[k]);
        }
    }
}

__global__ __launch_bounds__(256)
void decode_out(const unsigned* __restrict__ y8, float* __restrict__ out) {
    int idx = blockIdx.x * 256 + threadIdx.x;
    if (idx < NN * 8) out[idx] = dec(y8[idx]);
}

// ---------------- launch ----------------

extern "C" void kernel_launch(void* const* d_in, const int* in_sizes, int n_in,
                              void* d_out, int out_size, void* d_ws, size_t ws_size,
                              hipStream_t stream) {
    const float* x0 = (const float*)d_in[0];
    const int*   ei = (const int*)d_in[1];
    const float* w1[4] = {(const float*)d_in[3],  (const float*)d_in[9],
                          (const float*)d_in[15], (const float*)d_in[21]};
    const float* b1[4] = {(const float*)d_in[4],  (const float*)d_in[10],
                          (const float*)d_in[16], (const float*)d_in[22]};
    const float* w2[4] = {(const float*)d_in[5],  (const float*)d_in[11],
                          (const float*)d_in[17], (const float*)d_in[23]};
    const float* b2[4] = {(const float*)d_in[6],  (const float*)d_in[12],
                          (const float*)d_in[18], (const float*)d_in[24]};
    const float* gg[3] = {(const float*)d_in[7],  (const float*)d_in[13],
                          (const float*)d_in[19]};
    const float* be[3] = {(const float*)d_in[8],  (const float*)d_in[14],
                          (const float*)d_in[20]};

    char* p = (char*)d_ws;
    auto alloc = [&](size_t bytes) -> char* {
        char* r = p;
        p += (bytes + 255) & ~(size_t)255;
        return r;
    };
    int*      cnt     = (int*)alloc((size_t)NN * 4);
    int*      part    = (int*)alloc((size_t)NBS * 4);
    int*      row_off = (int*)alloc((size_t)(NN + 1) * 4);
    int*      cur     = (int*)alloc((size_t)NN * 4);
    int*      csr_s   = (int*)alloc((size_t)EE * 4);
    int*      csr_d   = (int*)alloc((size_t)EE * 4);
    float*    st      = (float*)alloc(3 * 128 * 4);
    float*    a0      = (float*)alloc((size_t)NN * 64 * 4);   // reused for a0_8
    unsigned* y       = (unsigned*)alloc((size_t)NN * 64 * 4);
    unsigned* y8      = (unsigned*)alloc((size_t)NN * 8 * 4);
    unsigned short* xb0 = (unsigned short*)alloc((size_t)NN * 64 * 2);
    unsigned short* xbA = (unsigned short*)alloc((size_t)NN * 64 * 2);
    unsigned short* xbB = xb0;

    hipMemsetAsync(cnt, 0, (size_t)NN * 4, stream);
    hipMemsetAsync(st, 0, 3 * 128 * 4, stream);

    count_k<<<(EE + 255) / 256, 256, 0, stream>>>(ei, cnt);
    scan_part<<<NBS, 256, 0, stream>>>(cnt, part);
    scan_top<<<1, 256, 0, stream>>>(part);
    scan_fin<<<NBS, 256, 0, stream>>>(cnt, part, row_off, cur);
    scatter_k<<<(EE + 255) / 256, 256, 0, stream>>>(ei, cur, csr_s, csr_d);

    // layer 0 input prep: fp32->bf16 + a0 GEMM + zero y/y8
    cvt_a0<<<NBF, 256, 0, stream>>>(x0, w1[0], b1[0], xb0, a0, y, y8);

    // layer 0
    edge_mfma64<<<NBLK64, 256, 0, stream>>>(xb0, a0, w1[0], w2[0], b2[0],
                                            csr_s, csr_d, y);
    bn_stats<<<512, 256, 0, stream>>>(y, st);
    bn_a0_64<<<NBF, 256, 0, stream>>>(y, st, gg[0], be[0], w1[1], b1[1], xbA, a0);

    // layer 1
    edge_mfma64<<<NBLK64, 256, 0, stream>>>(xbA, a0, w1[1], w2[1], b2[1],
                                            csr_s, csr_d, y);
    bn_stats<<<512, 256, 0, stream>>>(y, st + 128);
    bn_a0_64<<<NBF, 256, 0, stream>>>(y, st + 128, gg[1], be[1], w1[2], b1[2], xbB, a0);

    // layer 2
    edge_mfma64<<<NBLK64, 256, 0, stream>>>(xbB, a0, w1[2], w2[2], b2[2],
                                            csr_s, csr_d, y);
    bn_stats<<<512, 256, 0, stream>>>(y, st + 256);
    bn_a0_8<<<NBF, 256, 0, stream>>>(y, st + 256, gg[2], be[2], w1[3], b1[3], xbA, a0);

    // layer 3: xbA -> d_out [N,8]
    edge_mfma16<<<NBLK16, 256, 0, stream>>>(xbA, a0, w1[3], w2[3], b2[3],
                                            csr_s, csr_d, y8);
    decode_out<<<(NN * 8 + 255) / 256, 256, 0, stream>>>(y8, (float*)d_out);
}

// Round 11
// 635.546 us; speedup vs baseline: 1.0039x; 1.0039x over previous
//
#include <hip/hip_runtime.h>
#include <hip/hip_bf16.h>
#include <math.h>

#define NN 50000
#define EE 800000
#define NT (EE / 16)          // 50000 flat 16-edge tiles (exact)
#define NTN (NN / 16)         // 3125 node tiles

// edge_mfma64: 1536 blocks = exactly 6/CU (LDS cap); balanced wave partition
#define NBLK64 1536
#define NW64 (NBLK64 * 4)     // 6144 waves
#define B64 (NT / NW64)       // 8
#define R64 (NT % NW64)       // 848

// edge_mfma16: small LDS -> 8 blocks/CU
#define NBLK16 2048
#define NW16 (NBLK16 * 4)     // 8192 waves
#define B16 (NT / NW16)       // 6
#define R16 (NT % NW16)       // 848

// bn/cvt kernels: 4 tiles/wave — amortizes the per-wave weight-fragment
// preamble (~128 scattered loads/lane). NBF=782 (R10) quadrupled that fixed
// cost for 1 tile/wave and regressed ~100 µs.
#define NBF 196
#define NWF (NBF * 4)         // 784 waves

typedef short s8v __attribute__((ext_vector_type(8)));   // 8 x bf16 (4 VGPRs)
typedef float f4v __attribute__((ext_vector_type(4)));   // MFMA C/D

__device__ __forceinline__ short f2bf(float f) {         // fp32 -> bf16 RNE
    unsigned u = __float_as_uint(f);
    u += 0x7fffu + ((u >> 16) & 1u);
    return (short)(u >> 16);
}

// monotone fp32 <-> uint encode for atomicMax-based segment max.
// key 0 (memset) < enc(any float) -> "never touched" -> decodes to 0.
__device__ __forceinline__ unsigned enc(float f) {
    unsigned u = __float_as_uint(f);
    return (u & 0x80000000u) ? ~u : (u | 0x80000000u);
}
__device__ __forceinline__ float dec(unsigned k) {
    if (k == 0u) return 0.0f;                            // empty segment -> 0
    unsigned u = (k & 0x80000000u) ? (k & 0x7fffffffu) : ~k;
    return __uint_as_float(u);
}

// mish(x) = x * (e^{2x}+2e^x) / (e^{2x}+2e^x+2); guard large x
__device__ __forceinline__ float mish_fast(float v) {
    float t = __expf(v);
    float s = t * (t + 2.0f);
    float r = v * s * __builtin_amdgcn_rcpf(s + 2.0f);
    return (v > 15.0f) ? v : r;
}

#define MFMA16(a, b, c) __builtin_amdgcn_mfma_f32_16x16x32_bf16(a, b, c, 0, 0, 0)

// ---------------- CSR build (dst-sorted edge list) ----------------

__global__ __launch_bounds__(256) void count_k(const int* __restrict__ ei,
                                               int* __restrict__ cnt) {
    int e = blockIdx.x * 256 + threadIdx.x;
    if (e < EE) atomicAdd(&cnt[ei[EE + e]], 1);   // row 1 = dst
}

#define NBS 196                                    // ceil(NN/256)

__global__ __launch_bounds__(256) void scan_part(const int* __restrict__ cnt,
                                                 int* __restrict__ part) {
    int t = threadIdx.x, i = blockIdx.x * 256 + t;
    __shared__ int ps[256];
    ps[t] = (i < NN) ? cnt[i] : 0;
    __syncthreads();
    for (int off = 128; off > 0; off >>= 1) {
        if (t < off) ps[t] += ps[t + off];
        __syncthreads();
    }
    if (t == 0) part[blockIdx.x] = ps[0];
}

__global__ __launch_bounds__(256) void scan_top(int* __restrict__ part) {
    int t = threadIdx.x;
    int v = (t < NBS) ? part[t] : 0;
    __shared__ int ps[256];
    ps[t] = v;
    __syncthreads();
    for (int off = 1; off < 256; off <<= 1) {
        int u = (t >= off) ? ps[t - off] : 0;
        __syncthreads();
        ps[t] += u;
        __syncthreads();
    }
    if (t < NBS) part[t] = ps[t] - v;              // exclusive
}

__global__ __launch_bounds__(256) void scan_fin(const int* __restrict__ cnt,
                                                const int* __restrict__ part,
                                                int* __restrict__ row_off,
                                                int* __restrict__ cur) {
    int t = threadIdx.x, i = blockIdx.x * 256 + t;
    int v = (i < NN) ? cnt[i] : 0;
    __shared__ int ps[256];
    ps[t] = v;
    __syncthreads();
    for (int off = 1; off < 256; off <<= 1) {
        int u = (t >= off) ? ps[t - off] : 0;
        __syncthreads();
        ps[t] += u;
        __syncthreads();
    }
    int excl = ps[t] - v + part[blockIdx.x];
    if (i < NN) {
        row_off[i] = excl;
        cur[i] = excl;
        if (i == NN - 1) row_off[NN] = excl + v;
    }
}

__global__ __launch_bounds__(256) void scatter_k(const int* __restrict__ ei,
                                                 int* __restrict__ cur,
                                                 int* __restrict__ csr_src,
                                                 int* __restrict__ csr_dst) {
    int e = blockIdx.x * 256 + threadIdx.x;
    if (e < EE) {
        int d = ei[EE + e];
        int p = atomicAdd(&cur[d], 1);
        csr_src[p] = ei[e];
        csr_dst[p] = d;
    }
}

// -------- layer-0 fused: fp32->bf16 convert + a0 GEMM + zero y/y8 --------
// a0 output transposed within a row: a0[n*64 + i*4 + nb] holds ch nb*16+i.

__global__ __launch_bounds__(256)
void cvt_a0(const float* __restrict__ x, const float* __restrict__ w1,
            const float* __restrict__ b1, unsigned short* __restrict__ xb,
            float* __restrict__ a0, unsigned* __restrict__ y,
            unsigned* __restrict__ y8) {
    const int tid = threadIdx.x;
    const int lane = tid & 63;
    const int wid = blockIdx.x * 4 + (tid >> 6);
    const int i = lane & 15, q = lane >> 4;
    s8v wf[4][2];
#pragma unroll
    for (int nb = 0; nb < 4; nb++)
#pragma unroll
        for (int kh = 0; kh < 2; kh++)
#pragma unroll
            for (int j = 0; j < 8; j++) {
                int k = kh * 32 + q * 8 + j, n = nb * 16 + i;
                wf[nb][kh][j] = f2bf(w1[k * 64 + n] - w1[(64 + k) * 64 + n]);
            }
    float bia[4];
#pragma unroll
    for (int nb = 0; nb < 4; nb++) bia[nb] = b1[nb * 16 + i];

    for (int t = wid; t < NTN; t += NWF) {
        const int row = t * 16 + i;
        const float* xr = x + (size_t)row * 64 + q * 8;
        f4v x0 = *(const f4v*)xr,        x1 = *(const f4v*)(xr + 4);
        f4v x2 = *(const f4v*)(xr + 32), x3 = *(const f4v*)(xr + 36);
        s8v af0, af1;
#pragma unroll
        for (int j = 0; j < 4; j++) {
            af0[j] = f2bf(x0[j]); af0[4 + j] = f2bf(x1[j]);
            af1[j] = f2bf(x2[j]); af1[4 + j] = f2bf(x3[j]);
        }
        unsigned short* xw = xb + (size_t)row * 64 + q * 8;
        *(s8v*)xw = af0;
        *(s8v*)(xw + 32) = af1;
        const int rowq = t * 16 + q * 4;
#pragma unroll
        for (int nb = 0; nb < 4; nb++) {
            f4v c = {0.f, 0.f, 0.f, 0.f};
            c = MFMA16(af0, wf[nb][0], c);
            c = MFMA16(af1, wf[nb][1], c);
#pragma unroll
            for (int r = 0; r < 4; r++)
                a0[(size_t)(rowq + r) * 64 + i * 4 + nb] = c[r] + bia[nb];
        }
    }
    // zero the atomic-max accumulators (replaces two memset dispatches)
    const int gt = blockIdx.x * 256 + tid, gs = NBF * 256;
    for (int idx = gt; idx < NN * 64; idx += gs) y[idx] = 0u;
    for (int idx = gt; idx < NN * 8; idx += gs) y8[idx] = 0u;
}

// -------- fused BN apply + bf16 emit + NEXT layer's a0 GEMM + y re-zero ----

__global__ __launch_bounds__(256)
void bn_a0_64(unsigned* __restrict__ yk, const float* __restrict__ st,
              const float* __restrict__ g, const float* __restrict__ be,
              const float* __restrict__ w1n, const float* __restrict__ b1n,
              unsigned short* __restrict__ xbout, float* __restrict__ a0out) {
    __shared__ float sa[64], sb[64];
    const int tid = threadIdx.x;
    if (tid < 64) {
        float mu  = st[tid] * (1.0f / NN);
        float var = st[64 + tid] * (1.0f / NN) - mu * mu;
        float sc  = rsqrtf(var + 1e-5f) * g[tid];
        sa[tid] = sc;
        sb[tid] = be[tid] - mu * sc;
    }
    __syncthreads();
    const int lane = tid & 63;
    const int wid = blockIdx.x * 4 + (tid >> 6);
    const int i = lane & 15, q = lane >> 4;

    s8v wf[4][2];
#pragma unroll
    for (int nb = 0; nb < 4; nb++)
#pragma unroll
        for (int kh = 0; kh < 2; kh++)
#pragma unroll
            for (int j = 0; j < 8; j++) {
                int k = kh * 32 + q * 8 + j, n = nb * 16 + i;
                wf[nb][kh][j] = f2bf(w1n[k * 64 + n] - w1n[(64 + k) * 64 + n]);
            }
    float bia[4];
#pragma unroll
    for (int nb = 0; nb < 4; nb++) bia[nb] = b1n[nb * 16 + i];

    // per-lane norm constants for its 16 channels (k = kh*32 + q*8 + j)
    f4v a00 = *(const f4v*)(sa + q * 8),      a01 = *(const f4v*)(sa + q * 8 + 4);
    f4v a10 = *(const f4v*)(sa + 32 + q * 8), a11 = *(const f4v*)(sa + 36 + q * 8);
    f4v b00 = *(const f4v*)(sb + q * 8),      b01 = *(const f4v*)(sb + q * 8 + 4);
    f4v b10 = *(const f4v*)(sb + 32 + q * 8), b11 = *(const f4v*)(sb + 36 + q * 8);

    const uint4 z4 = {0u, 0u, 0u, 0u};
    for (int t = wid; t < NTN; t += NWF) {
        const int row = t * 16 + i;
        unsigned* yr = yk + (size_t)row * 64 + q * 8;
        uint4 u0 = *(const uint4*)yr,        u1 = *(const uint4*)(yr + 4);
        uint4 u2 = *(const uint4*)(yr + 32), u3 = *(const uint4*)(yr + 36);
        s8v af0, af1;
        af0[0] = f2bf(dec(u0.x) * a00[0] + b00[0]);
        af0[1] = f2bf(dec(u0.y) * a00[1] + b00[1]);
        af0[2] = f2bf(dec(u0.z) * a00[2] + b00[2]);
        af0[3] = f2bf(dec(u0.w) * a00[3] + b00[3]);
        af0[4] = f2bf(dec(u1.x) * a01[0] + b01[0]);
        af0[5] = f2bf(dec(u1.y) * a01[1] + b01[1]);
        af0[6] = f2bf(dec(u1.z) * a01[2] + b01[2]);
        af0[7] = f2bf(dec(u1.w) * a01[3] + b01[3]);
        af1[0] = f2bf(dec(u2.x) * a10[0] + b10[0]);
        af1[1] = f2bf(dec(u2.y) * a10[1] + b10[1]);
        af1[2] = f2bf(dec(u2.z) * a10[2] + b10[2]);
        af1[3] = f2bf(dec(u2.w) * a10[3] + b10[3]);
        af1[4] = f2bf(dec(u3.x) * a11[0] + b11[0]);
        af1[5] = f2bf(dec(u3.y) * a11[1] + b11[1]);
        af1[6] = f2bf(dec(u3.z) * a11[2] + b11[2]);
        af1[7] = f2bf(dec(u3.w) * a11[3] + b11[3]);

        unsigned short* xw = xbout + (size_t)row * 64 + q * 8;
        *(s8v*)xw = af0;
        *(s8v*)(xw + 32) = af1;
        *(uint4*)yr = z4;        *(uint4*)(yr + 4) = z4;    // re-zero for next layer
        *(uint4*)(yr + 32) = z4; *(uint4*)(yr + 36) = z4;

        const int rowq = t * 16 + q * 4;
#pragma unroll
        for (int nb = 0; nb < 4; nb++) {
            f4v c = {0.f, 0.f, 0.f, 0.f};
            c = MFMA16(af0, wf[nb][0], c);
            c = MFMA16(af1, wf[nb][1], c);
#pragma unroll
            for (int r = 0; r < 4; r++)
                a0out[(size_t)(rowq + r) * 64 + i * 4 + nb] = c[r] + bia[nb];
        }
    }
}

// variant for layer 2 -> 3: next layer dout = 8

__global__ __launch_bounds__(256)
void bn_a0_8(unsigned* __restrict__ yk, const float* __restrict__ st,
             const float* __restrict__ g, const float* __restrict__ be,
             const float* __restrict__ w1n, const float* __restrict__ b1n,
             unsigned short* __restrict__ xbout, float* __restrict__ a08) {
    __shared__ float sa[64], sb[64];
    const int tid = threadIdx.x;
    if (tid < 64) {
        float mu  = st[tid] * (1.0f / NN);
        float var = st[64 + tid] * (1.0f / NN) - mu * mu;
        float sc  = rsqrtf(var + 1e-5f) * g[tid];
        sa[tid] = sc;
        sb[tid] = be[tid] - mu * sc;
    }
    __syncthreads();
    const int lane = tid & 63;
    const int wid = blockIdx.x * 4 + (tid >> 6);
    const int i = lane & 15, q = lane >> 4;

    s8v wf[2];
#pragma unroll
    for (int kh = 0; kh < 2; kh++)
#pragma unroll
        for (int j = 0; j < 8; j++) {
            int k = kh * 32 + q * 8 + j;
            wf[kh][j] = (i < 8) ? f2bf(w1n[k * 8 + i] - w1n[(64 + k) * 8 + i]) : (short)0;
        }
    const float bia = (i < 8) ? b1n[i] : 0.0f;

    f4v a00 = *(const f4v*)(sa + q * 8),      a01 = *(const f4v*)(sa + q * 8 + 4);
    f4v a10 = *(const f4v*)(sa + 32 + q * 8), a11 = *(const f4v*)(sa + 36 + q * 8);
    f4v b00 = *(const f4v*)(sb + q * 8),      b01 = *(const f4v*)(sb + q * 8 + 4);
    f4v b10 = *(const f4v*)(sb + 32 + q * 8), b11 = *(const f4v*)(sb + 36 + q * 8);

    for (int t = wid; t < NTN; t += NWF) {
        const int row = t * 16 + i;
        const unsigned* yr = yk + (size_t)row * 64 + q * 8;
        uint4 u0 = *(const uint4*)yr,        u1 = *(const uint4*)(yr + 4);
        uint4 u2 = *(const uint4*)(yr + 32), u3 = *(const uint4*)(yr + 36);
        s8v af0, af1;
        af0[0] = f2bf(dec(u0.x) * a00[0] + b00[0]);
        af0[1] = f2bf(dec(u0.y) * a00[1] + b00[1]);
        af0[2] = f2bf(dec(u0.z) * a00[2] + b00[2]);
        af0[3] = f2bf(dec(u0.w) * a00[3] + b00[3]);
        af0[4] = f2bf(dec(u1.x) * a01[0] + b01[0]);
        af0[5] = f2bf(dec(u1.y) * a01[1] + b01[1]);
        af0[6] = f2bf(dec(u1.z) * a01[2] + b01[2]);
        af0[7] = f2bf(dec(u1.w) * a01[3] + b01[3]);
        af1[0] = f2bf(dec(u2.x) * a10[0] + b10[0]);
        af1[1] = f2bf(dec(u2.y) * a10[1] + b10[1]);
        af1[2] = f2bf(dec(u2.z) * a10[2] + b10[2]);
        af1[3] = f2bf(dec(u2.w) * a10[3] + b10[3]);
        af1[4] = f2bf(dec(u3.x) * a11[0] + b11[0]);
        af1[5] = f2bf(dec(u3.y) * a11[1] + b11[1]);
        af1[6] = f2bf(dec(u3.z) * a11[2] + b11[2]);
        af1[7] = f2bf(dec(u3.w) * a11[3] + b11[3]);

        unsigned short* xw = xbout + (size_t)row * 64 + q * 8;
        *(s8v*)xw = af0;
        *(s8v*)(xw + 32) = af1;

        f4v c = {0.f, 0.f, 0.f, 0.f};
        c = MFMA16(af0, wf[0], c);
        c = MFMA16(af1, wf[1], c);
        if (i < 8) {
            const int rowq = t * 16 + q * 4;
#pragma unroll
            for (int r = 0; r < 4; r++)
                a08[(size_t)(rowq + r) * 8 + i] = c[r] + bia;
        }
    }
}

// ------- edge-major fused MLP + segmented max, dout=64 -------
// (inner loop identical to R8-R10; balanced wave partition over 1536 blocks)

__global__ __launch_bounds__(256)
void edge_mfma64(const unsigned short* __restrict__ xb, const float* __restrict__ a0,
                 const float* __restrict__ w1, const float* __restrict__ w2,
                 const float* __restrict__ b2,
                 const int* __restrict__ csr_src, const int* __restrict__ csr_dst,
                 unsigned* __restrict__ y) {
    __shared__ float uld[4][16 * 68];                 // per-wave tile, stride 68
    __shared__ int dseg[4][2][20];                    // per-wave dst ids, dbuf
    __shared__ short w2l[8 * 64 * 8];                 // W2 frags: (nb*2+kh, lane, j)
    const int lane = threadIdx.x & 63;
    const int wv = threadIdx.x >> 6;
    const int wid = blockIdx.x * 4 + wv;
    const int i = lane & 15, q = lane >> 4;
    float* up = &uld[wv][0];

    // W1bot fragments stay register-resident (32 VGPRs)
    s8v w1f[4][2];
#pragma unroll
    for (int nb = 0; nb < 4; nb++)
#pragma unroll
        for (int kh = 0; kh < 2; kh++)
#pragma unroll
            for (int j = 0; j < 8; j++) {
                int k = kh * 32 + q * 8 + j, n = nb * 16 + i;
                w1f[nb][kh][j] = f2bf(w1[(64 + k) * 64 + n]);
            }
    // stage this wave's nb(=wv) W2 fragments into shared LDS
    {
        const int nb = wv;
#pragma unroll
        for (int kh = 0; kh < 2; kh++) {
            s8v uu;
#pragma unroll
            for (int j = 0; j < 8; j++) {
                int k = kh * 32 + q * 8 + j;
                uu[j] = f2bf(w2[k * 64 + nb * 16 + i]);
            }
            *(s8v*)(w2l + ((nb * 2 + kh) * 64 + lane) * 8) = uu;
        }
    }
    __syncthreads();

    const float b2c = b2[lane];                       // channel = lane (scan)

    // balanced partition: first R64 waves get B64+1 tiles, rest B64
    int t = wid * B64 + (wid < R64 ? wid : R64);
    const int tend = t + B64 + (wid < R64 ? 1 : 0);

    s8v af0_c, af1_c;
    {
        int s0 = csr_src[t * 16 + i];
        const unsigned short* xr = xb + (size_t)s0 * 64;
        af0_c = *(const s8v*)(xr + q * 8);
        af1_c = *(const s8v*)(xr + 32 + q * 8);
    }
    int src_n = (t + 1 < tend) ? csr_src[(t + 1) * 16 + i] : 0;
    if (lane < 17) {
        int e = t * 16 + lane;
        dseg[wv][t & 1][lane] = (e < EE) ? csr_dst[e] : -1;
    }
    asm volatile("s_waitcnt lgkmcnt(0)" ::: "memory");
    int dq_c[4];
#pragma unroll
    for (int r = 0; r < 4; r++) dq_c[r] = dseg[wv][t & 1][q * 4 + r];
    f4v a0r_c[4];
#pragma unroll
    for (int r = 0; r < 4; r++)
        a0r_c[r] = *(const f4v*)(a0 + (size_t)dq_c[r] * 64 + i * 4);

    float run = -INFINITY;                            // per-channel running max

    for (; t < tend; t++) {
        const bool has_n = (t + 1) < tend;
        int* dsg = &dseg[wv][t & 1][0];
        int* dsg_n = &dseg[wv][(t + 1) & 1][0];

        if (has_n && lane < 17) {
            int e = (t + 1) * 16 + lane;
            dsg_n[lane] = (e < EE) ? csr_dst[e] : -1;
        }
        s8v af0_n = {0,0,0,0,0,0,0,0}, af1_n = {0,0,0,0,0,0,0,0};
        if (has_n) {
            const unsigned short* xr = xb + (size_t)src_n * 64;
            af0_n = *(const s8v*)(xr + q * 8);
            af1_n = *(const s8v*)(xr + 32 + q * 8);
        }
        int src_nn = (t + 2 < tend) ? csr_src[(t + 2) * 16 + i] : 0;

        // GEMM1
        f4v c0 = {0.f, 0.f, 0.f, 0.f}, c1 = c0, c2 = c0, c3 = c0;
        c0 = MFMA16(af0_c, w1f[0][0], c0); c0 = MFMA16(af1_c, w1f[0][1], c0);
        c1 = MFMA16(af0_c, w1f[1][0], c1); c1 = MFMA16(af1_c, w1f[1][1], c1);
        c2 = MFMA16(af0_c, w1f[2][0], c2); c2 = MFMA16(af1_c, w1f[2][1], c2);
        c3 = MFMA16(af0_c, w1f[3][0], c3); c3 = MFMA16(af1_c, w1f[3][1], c3);

        asm volatile("" ::: "memory");
#pragma unroll
        for (int r = 0; r < 4; r++) {
            const int ro = (q * 4 + r) * 68 + i;
            up[ro +  0] = mish_fast(c0[r] + a0r_c[r][0]);
            up[ro + 16] = mish_fast(c1[r] + a0r_c[r][1]);
            up[ro + 32] = mish_fast(c2[r] + a0r_c[r][2]);
            up[ro + 48] = mish_fast(c3[r] + a0r_c[r][3]);
        }
        asm volatile("s_waitcnt lgkmcnt(0)" ::: "memory");   // wait#2

        int dq_n[4];
        f4v a0r_n[4];
        if (has_n) {
#pragma unroll
            for (int r = 0; r < 4; r++) dq_n[r] = dsg_n[q * 4 + r];
#pragma unroll
            for (int r = 0; r < 4; r++)
                a0r_n[r] = *(const f4v*)(a0 + (size_t)dq_n[r] * 64 + i * 4);
        }

        s8v uf[2];
#pragma unroll
        for (int kh = 0; kh < 2; kh++) {
            const f4v* rp = (const f4v*)(up + i * 68 + kh * 32 + q * 8);
            f4v v0 = rp[0], v1 = rp[1];
            s8v uu;
            uu[0] = f2bf(v0[0]); uu[1] = f2bf(v0[1]);
            uu[2] = f2bf(v0[2]); uu[3] = f2bf(v0[3]);
            uu[4] = f2bf(v1[0]); uu[5] = f2bf(v1[1]);
            uu[6] = f2bf(v1[2]); uu[7] = f2bf(v1[3]);
            uf[kh] = uu;
        }
        asm volatile("" ::: "memory");

        // GEMM2 (B fragments streamed from shared LDS)
        f4v cc[4];
#pragma unroll
        for (int nb = 0; nb < 4; nb++) {
            s8v b0 = *(const s8v*)(w2l + ((nb * 2 + 0) * 64 + lane) * 8);
            s8v b1v = *(const s8v*)(w2l + ((nb * 2 + 1) * 64 + lane) * 8);
            f4v c = {0.f, 0.f, 0.f, 0.f};
            c = MFMA16(uf[0], b0, c);
            c = MFMA16(uf[1], b1v, c);
            cc[nb] = c;
        }

#pragma unroll
        for (int nb = 0; nb < 4; nb++)
#pragma unroll
            for (int r = 0; r < 4; r++)
                up[(q * 4 + r) * 68 + nb * 16 + i] = cc[nb][r];
        asm volatile("s_waitcnt lgkmcnt(0)" ::: "memory");   // wait#3

        float v[16];
#pragma unroll
        for (int row = 0; row < 16; row++) v[row] = up[row * 68 + lane];

        int dcur = dsg[0];
#pragma unroll
        for (int row = 0; row < 16; row++) {
            run = fmaxf(run, v[row]);
            int dn = (row < 15) ? dsg[row + 1] : (has_n ? dsg[16] : -1);
            if (dcur != dn) {
                atomicMax(&y[(size_t)dcur * 64 + lane], enc(run + b2c));
                run = -INFINITY;
            }
            dcur = dn;
        }
        asm volatile("s_waitcnt lgkmcnt(0)" ::: "memory");  // WAR guard

        src_n = src_nn;
        af0_c = af0_n; af1_c = af1_n;
#pragma unroll
        for (int r = 0; r < 4; r++) a0r_c[r] = a0r_n[r];
    }
}

// ------- edge-major final layer, dout=8; balanced partition over 2048 blocks -

__global__ __launch_bounds__(256)
void edge_mfma16(const unsigned short* __restrict__ xb, const float* __restrict__ a0,
                 const float* __restrict__ w1, const float* __restrict__ w2,
                 const float* __restrict__ b2,
                 const int* __restrict__ csr_src, const int* __restrict__ csr_dst,
                 unsigned* __restrict__ y8) {
    __shared__ float uld[4][16 * 20];
    __shared__ int dseg[4][2][20];
    const int lane = threadIdx.x & 63;
    const int wv = threadIdx.x >> 6;
    const int wid = blockIdx.x * 4 + wv;
    const int i = lane & 15, q = lane >> 4;
    float* up = &uld[wv][0];

    s8v w1f[2], w2f;
#pragma unroll
    for (int kh = 0; kh < 2; kh++)
#pragma unroll
        for (int j = 0; j < 8; j++) {
            int k = kh * 32 + q * 8 + j;
            w1f[kh][j] = (i < 8) ? f2bf(w1[(64 + k) * 8 + i]) : (short)0;
        }
#pragma unroll
    for (int j = 0; j < 8; j++)
        w2f[j] = (q == 0 && i < 8) ? f2bf(w2[j * 8 + i]) : (short)0;
    const float b2c = (lane < 8) ? b2[lane] : 0.0f;

    int t = wid * B16 + (wid < R16 ? wid : R16);
    const int tend = t + B16 + (wid < R16 ? 1 : 0);

    s8v af0_c, af1_c;
    {
        int s0 = csr_src[t * 16 + i];
        const unsigned short* xr = xb + (size_t)s0 * 64;
        af0_c = *(const s8v*)(xr + q * 8);
        af1_c = *(const s8v*)(xr + 32 + q * 8);
    }
    int src_n = (t + 1 < tend) ? csr_src[(t + 1) * 16 + i] : 0;
    if (lane < 17) {
        int e = t * 16 + lane;
        dseg[wv][t & 1][lane] = (e < EE) ? csr_dst[e] : -1;
    }
    asm volatile("s_waitcnt lgkmcnt(0)" ::: "memory");
    int dq_c[4];
#pragma unroll
    for (int r = 0; r < 4; r++) dq_c[r] = dseg[wv][t & 1][q * 4 + r];
    float av_c[4];
#pragma unroll
    for (int r = 0; r < 4; r++)
        av_c[r] = (i < 8) ? a0[(size_t)dq_c[r] * 8 + i] : 0.0f;

    float run = -INFINITY;

    for (; t < tend; t++) {
        const bool has_n = (t + 1) < tend;
        int* dsg = &dseg[wv][t & 1][0];
        int* dsg_n = &dseg[wv][(t + 1) & 1][0];

        if (has_n && lane < 17) {
            int e = (t + 1) * 16 + lane;
            dsg_n[lane] = (e < EE) ? csr_dst[e] : -1;
        }
        s8v af0_n = {0,0,0,0,0,0,0,0}, af1_n = {0,0,0,0,0,0,0,0};
        if (has_n) {
            const unsigned short* xr = xb + (size_t)src_n * 64;
            af0_n = *(const s8v*)(xr + q * 8);
            af1_n = *(const s8v*)(xr + 32 + q * 8);
        }
        int src_nn = (t + 2 < tend) ? csr_src[(t + 2) * 16 + i] : 0;

        f4v c = {0.f, 0.f, 0.f, 0.f};
        c = MFMA16(af0_c, w1f[0], c);
        c = MFMA16(af1_c, w1f[1], c);

        asm volatile("" ::: "memory");
#pragma unroll
        for (int r = 0; r < 4; r++)
            up[(q * 4 + r) * 20 + i] = mish_fast(c[r] + av_c[r]);   // cols 8..15 = 0
        asm volatile("s_waitcnt lgkmcnt(0)" ::: "memory");           // wait#2

        int dq_n[4];
        float av_n[4] = {0, 0, 0, 0};
        if (has_n) {
#pragma unroll
            for (int r = 0; r < 4; r++) dq_n[r] = dsg_n[q * 4 + r];
#pragma unroll
            for (int r = 0; r < 4; r++)
                av_n[r] = (i < 8) ? a0[(size_t)dq_n[r] * 8 + i] : 0.0f;
        }

        s8v uf = {0,0,0,0,0,0,0,0};
        if (q < 2) {                                   // k = q*8+j < 16
            const f4v* rp = (const f4v*)(up + i * 20 + q * 8);
            f4v v0 = rp[0], v1 = rp[1];
            uf[0] = f2bf(v0[0]); uf[1] = f2bf(v0[1]);
            uf[2] = f2bf(v0[2]); uf[3] = f2bf(v0[3]);
            uf[4] = f2bf(v1[0]); uf[5] = f2bf(v1[1]);
            uf[6] = f2bf(v1[2]); uf[7] = f2bf(v1[3]);
        }
        asm volatile("" ::: "memory");

        f4v cc = {0.f, 0.f, 0.f, 0.f};
        cc = MFMA16(uf, w2f, cc);

#pragma unroll
        for (int r = 0; r < 4; r++)
            up[(q * 4 + r) * 20 + i] = cc[r];
        asm volatile("s_waitcnt lgkmcnt(0)" ::: "memory");           // wait#3

        float v[16];
#pragma unroll
        for (int row = 0; row < 16; row++) v[row] = up[row * 20 + (lane & 7)];

        int dcur = dsg[0];
#pragma unroll
        for (int row = 0; row < 16; row++) {
            run = fmaxf(run, v[row]);
            int dn = (row < 15) ? dsg[row + 1] : (has_n ? dsg[16] : -1);
            if (dcur != dn) {
                if (lane < 8)
                    atomicMax(&y8[(size_t)dcur * 8 + lane], enc(run + b2c));
                run = -INFINITY;
            }
            dcur = dn;
        }
        asm volatile("s_waitcnt lgkmcnt(0)" ::: "memory");

        src_n = src_nn;
        af0_c = af0_n; af1_c = af1_n;
#pragma unroll
        for (int r = 0; r < 4; r++) av_c[r] = av_n[r];
    }
}

// ---------------- BatchNorm stats (vectorized: uint4 per thread) ------------

__global__ __launch_bounds__(256)
void bn_stats(const unsigned* __restrict__ yk, float* __restrict__ st) {
    const int tid = threadIdx.x;
    const int c4 = (tid & 15) * 4;                 // 4-channel group
    const int r = tid >> 4;                        // row slot (0..15)
    f4v s = {0.f, 0.f, 0.f, 0.f}, qq = s;
    for (int n = blockIdx.x * 16 + r; n < NN; n += gridDim.x * 16) {
        uint4 u = *(const uint4*)(yk + (size_t)n * 64 + c4);
        float v0 = dec(u.x), v1 = dec(u.y), v2 = dec(u.z), v3 = dec(u.w);
        s[0] += v0; s[1] += v1; s[2] += v2; s[3] += v3;
        qq[0] = fmaf(v0, v0, qq[0]); qq[1] = fmaf(v1, v1, qq[1]);
        qq[2] = fmaf(v2, v2, qq[2]); qq[3] = fmaf(v3, v3, qq[3]);
    }
    __shared__ float ls[1024], lq[1024];
    *(f4v*)(ls + tid * 4) = s;
    *(f4v*)(lq + tid * 4) = qq;
    __syncthreads();
    for (int off = 128; off >= 16; off >>= 1) {
        if (tid < off) {
            f4v a = *(f4v*)(ls + tid * 4), b = *(f4v*)(ls + (tid + off) * 4);
            f4v c = *(f4v*)(lq + tid * 4), d = *(f4v*)(lq + (tid + off) * 4);
            *(f4v*)(ls + tid * 4) = a + b;
            *(f4v*)(lq + tid * 4) = c + d;
        }
        __syncthreads();
    }
    if (tid < 16) {
        f4v a = *(f4v*)(ls + tid * 4), c = *(f4v*)(lq + tid * 4);
#pragma unroll
        for (int k = 0; k < 4; k++) {
            atomicAdd(&st[tid * 4 + k], a[k]);
            atomicAdd(&st[64 + tid * 4 + k], c[k]);
        }
    }
}

__global__ __launch_bounds__(256)
void decode_out(const unsigned* __restrict__ y8, float* __restrict__ out) {
    int idx = blockIdx.x * 256 + threadIdx.x;
    if (idx < NN * 8) out[idx] = dec(y8[idx]);
}

// ---------------- launch ----------------

extern "C" void kernel_launch(void* const* d_in, const int* in_sizes, int n_in,
                              void* d_out, int out_size, void* d_ws, size_t ws_size,
                              hipStream_t stream) {
    const float* x0 = (const float*)d_in[0];
    const int*   ei = (const int*)d_in[1];
    const float* w1[4] = {(const float*)d_in[3],  (const float*)d_in[9],
                          (const float*)d_in[15], (const float*)d_in[21]};
    const float* b1[4] = {(const float*)d_in[4],  (const float*)d_in[10],
                          (const float*)d_in[16], (const float*)d_in[22]};
    const float* w2[4] = {(const float*)d_in[5],  (const float*)d_in[11],
                          (const float*)d_in[17], (const float*)d_in[23]};
    const float* b2[4] = {(const float*)d_in[6],  (const float*)d_in[12],
                          (const float*)d_in[18], (const float*)d_in[24]};
    const float* gg[3] = {(const float*)d_in[7],  (const float*)d_in[13],
                          (const float*)d_in[19]};
    const float* be[3] = {(const float*)d_in[8],  (const float*)d_in[14],
                          (const float*)d_in[20]};

    char* p = (char*)d_ws;
    auto alloc = [&](size_t bytes) -> char* {
        char* r = p;
        p += (bytes + 255) & ~(size_t)255;
        return r;
    };
    int*      cnt     = (int*)alloc((size_t)NN * 4);
    int*      part    = (int*)alloc((size_t)NBS * 4);
    int*      row_off = (int*)alloc((size_t)(NN + 1) * 4);
    int*      cur     = (int*)alloc((size_t)NN * 4);
    int*      csr_s   = (int*)alloc((size_t)EE * 4);
    int*      csr_d   = (int*)alloc((size_t)EE * 4);
    float*    st      = (float*)alloc(3 * 128 * 4);
    float*    a0      = (float*)alloc((size_t)NN * 64 * 4);   // reused for a0_8
    unsigned* y       = (unsigned*)alloc((size_t)NN * 64 * 4);
    unsigned* y8      = (unsigned*)alloc((size_t)NN * 8 * 4);
    unsigned short* xb0 = (unsigned short*)alloc((size_t)NN * 64 * 2);
    unsigned short* xbA = (unsigned short*)alloc((size_t)NN * 64 * 2);
    unsigned short* xbB = xb0;

    hipMemsetAsync(cnt, 0, (size_t)NN * 4, stream);
    hipMemsetAsync(st, 0, 3 * 128 * 4, stream);

    count_k<<<(EE + 255) / 256, 256, 0, stream>>>(ei, cnt);
    scan_part<<<NBS, 256, 0, stream>>>(cnt, part);
    scan_top<<<1, 256, 0, stream>>>(part);
    scan_fin<<<NBS, 256, 0, stream>>>(cnt, part, row_off, cur);
    scatter_k<<<(EE + 255) / 256, 256, 0, stream>>>(ei, cur, csr_s, csr_d);

    // layer 0 input prep: fp32->bf16 + a0 GEMM + zero y/y8
    cvt_a0<<<NBF, 256, 0, stream>>>(x0, w1[0], b1[0], xb0, a0, y, y8);

    // layer 0
    edge_mfma64<<<NBLK64, 256, 0, stream>>>(xb0, a0, w1[0], w2[0], b2[0],
                                            csr_s, csr_d, y);
    bn_stats<<<512, 256, 0, stream>>>(y, st);
    bn_a0_64<<<NBF, 256, 0, stream>>>(y, st, gg[0], be[0], w1[1], b1[1], xbA, a0);

    // layer 1
    edge_mfma64<<<NBLK64, 256, 0, stream>>>(xbA, a0, w1[1], w2[1], b2[1],
                                            csr_s, csr_d, y);
    bn_stats<<<512, 256, 0, stream>>>(y, st + 128);
    bn_a0_64<<<NBF, 256, 0, stream>>>(y, st + 128, gg[1], be[1], w1[2], b1[2], xbB, a0);

    // layer 2
    edge_mfma64<<<NBLK64, 256, 0, stream>>>(xbB, a0, w1[2], w2[2], b2[2],
                                            csr_s, csr_d, y);
    bn_stats<<<512, 256, 0, stream>>>(y, st + 256);
    bn_a0_8<<<NBF, 256, 0, stream>>>(y, st + 256, gg[2], be[2], w1[3], b1[3], xbA, a0);

    // layer 3: xbA -> d_out [N,8]
    edge_mfma16<<<NBLK16, 256, 0, stream>>>(xbA, a0, w1[3], w2[3], b2[3],
                                            csr_s, csr_d, y8);
    decode_out<<<(NN * 8 + 255) / 256, 256, 0, stream>>>(y8, (float*)d_out);
}

// Round 12
// 519.902 us; speedup vs baseline: 1.2272x; 1.2224x over previous
//
#include <hip/hip_runtime.h>
#include <hip/hip_bf16.h>
#include <math.h>

#define NN 50000
#define EE 800000
#define NT (EE / 16)          // 50000 flat 16-edge tiles (exact)
#define NTN (NN / 16)         // 3125 node tiles

// edge_mfma64: 1536 blocks = exactly 6/CU (LDS cap); balanced wave partition
// (R10's one counter-verified win: 68 -> 63.5 us)
#define NBLK64 1536
#define NW64 (NBLK64 * 4)     // 6144 waves
#define B64 (NT / NW64)       // 8
#define R64 (NT % NW64)       // 848

// edge_mfma16 + CSR-era grid params: R9 verbatim (CHT chunking)
#define NBLK 1408
#define CHT 9                 // 1408*4*9 >= NT

// bn/cvt kernels: 4 tiles/wave (R9 verbatim)
#define NBF 196
#define NWF (NBF * 4)         // 784 waves

typedef short s8v __attribute__((ext_vector_type(8)));   // 8 x bf16 (4 VGPRs)
typedef float f4v __attribute__((ext_vector_type(4)));   // MFMA C/D

__device__ __forceinline__ short f2bf(float f) {         // fp32 -> bf16 RNE
    unsigned u = __float_as_uint(f);
    u += 0x7fffu + ((u >> 16) & 1u);
    return (short)(u >> 16);
}

// monotone fp32 <-> uint encode for atomicMax-based segment max.
// key 0 (memset) < enc(any float) -> "never touched" -> decodes to 0.
__device__ __forceinline__ unsigned enc(float f) {
    unsigned u = __float_as_uint(f);
    return (u & 0x80000000u) ? ~u : (u | 0x80000000u);
}
__device__ __forceinline__ float dec(unsigned k) {
    if (k == 0u) return 0.0f;                            // empty segment -> 0
    unsigned u = (k & 0x80000000u) ? (k & 0x7fffffffu) : ~k;
    return __uint_as_float(u);
}

// mish(x) = x * (e^{2x}+2e^x) / (e^{2x}+2e^x+2); guard large x
__device__ __forceinline__ float mish_fast(float v) {
    float t = __expf(v);
    float s = t * (t + 2.0f);
    float r = v * s * __builtin_amdgcn_rcpf(s + 2.0f);
    return (v > 15.0f) ? v : r;
}

#define MFMA16(a, b, c) __builtin_amdgcn_mfma_f32_16x16x32_bf16(a, b, c, 0, 0, 0)

// ---------------- CSR build (dst-sorted edge list) ----------------

__global__ __launch_bounds__(256) void count_k(const int* __restrict__ ei,
                                               int* __restrict__ cnt) {
    int e = blockIdx.x * 256 + threadIdx.x;
    if (e < EE) atomicAdd(&cnt[ei[EE + e]], 1);   // row 1 = dst
}

#define NBS 196                                    // ceil(NN/256)

__global__ __launch_bounds__(256) void scan_part(const int* __restrict__ cnt,
                                                 int* __restrict__ part) {
    int t = threadIdx.x, i = blockIdx.x * 256 + t;
    __shared__ int ps[256];
    ps[t] = (i < NN) ? cnt[i] : 0;
    __syncthreads();
    for (int off = 128; off > 0; off >>= 1) {
        if (t < off) ps[t] += ps[t + off];
        __syncthreads();
    }
    if (t == 0) part[blockIdx.x] = ps[0];
}

__global__ __launch_bounds__(256) void scan_top(int* __restrict__ part) {
    int t = threadIdx.x;
    int v = (t < NBS) ? part[t] : 0;
    __shared__ int ps[256];
    ps[t] = v;
    __syncthreads();
    for (int off = 1; off < 256; off <<= 1) {
        int u = (t >= off) ? ps[t - off] : 0;
        __syncthreads();
        ps[t] += u;
        __syncthreads();
    }
    if (t < NBS) part[t] = ps[t] - v;              // exclusive
}

__global__ __launch_bounds__(256) void scan_fin(const int* __restrict__ cnt,
                                                const int* __restrict__ part,
                                                int* __restrict__ row_off,
                                                int* __restrict__ cur) {
    int t = threadIdx.x, i = blockIdx.x * 256 + t;
    int v = (i < NN) ? cnt[i] : 0;
    __shared__ int ps[256];
    ps[t] = v;
    __syncthreads();
    for (int off = 1; off < 256; off <<= 1) {
        int u = (t >= off) ? ps[t - off] : 0;
        __syncthreads();
        ps[t] += u;
        __syncthreads();
    }
    int excl = ps[t] - v + part[blockIdx.x];
    if (i < NN) {
        row_off[i] = excl;
        cur[i] = excl;
        if (i == NN - 1) row_off[NN] = excl + v;
    }
}

__global__ __launch_bounds__(256) void scatter_k(const int* __restrict__ ei,
                                                 int* __restrict__ cur,
                                                 int* __restrict__ csr_src,
                                                 int* __restrict__ csr_dst) {
    int e = blockIdx.x * 256 + threadIdx.x;
    if (e < EE) {
        int d = ei[EE + e];
        int p = atomicAdd(&cur[d], 1);
        csr_src[p] = ei[e];
        csr_dst[p] = d;
    }
}

// -------- layer-0 fused: fp32->bf16 convert + a0 GEMM + zero y/y8 --------
// a0 output transposed within a row: a0[n*64 + i*4 + nb] holds ch nb*16+i.

__global__ __launch_bounds__(256)
void cvt_a0(const float* __restrict__ x, const float* __restrict__ w1,
            const float* __restrict__ b1, unsigned short* __restrict__ xb,
            float* __restrict__ a0, unsigned* __restrict__ y,
            unsigned* __restrict__ y8) {
    const int tid = threadIdx.x;
    const int lane = tid & 63;
    const int wid = blockIdx.x * 4 + (tid >> 6);
    const int i = lane & 15, q = lane >> 4;
    s8v wf[4][2];
#pragma unroll
    for (int nb = 0; nb < 4; nb++)
#pragma unroll
        for (int kh = 0; kh < 2; kh++)
#pragma unroll
            for (int j = 0; j < 8; j++) {
                int k = kh * 32 + q * 8 + j, n = nb * 16 + i;
                wf[nb][kh][j] = f2bf(w1[k * 64 + n] - w1[(64 + k) * 64 + n]);
            }
    float bia[4];
#pragma unroll
    for (int nb = 0; nb < 4; nb++) bia[nb] = b1[nb * 16 + i];

    for (int t = wid; t < NTN; t += NWF) {
        const int row = t * 16 + i;
        const float* xr = x + (size_t)row * 64 + q * 8;
        f4v x0 = *(const f4v*)xr,        x1 = *(const f4v*)(xr + 4);
        f4v x2 = *(const f4v*)(xr + 32), x3 = *(const f4v*)(xr + 36);
        s8v af0, af1;
#pragma unroll
        for (int j = 0; j < 4; j++) {
            af0[j] = f2bf(x0[j]); af0[4 + j] = f2bf(x1[j]);
            af1[j] = f2bf(x2[j]); af1[4 + j] = f2bf(x3[j]);
        }
        unsigned short* xw = xb + (size_t)row * 64 + q * 8;
        *(s8v*)xw = af0;
        *(s8v*)(xw + 32) = af1;
        const int rowq = t * 16 + q * 4;
#pragma unroll
        for (int nb = 0; nb < 4; nb++) {
            f4v c = {0.f, 0.f, 0.f, 0.f};
            c = MFMA16(af0, wf[nb][0], c);
            c = MFMA16(af1, wf[nb][1], c);
#pragma unroll
            for (int r = 0; r < 4; r++)
                a0[(size_t)(rowq + r) * 64 + i * 4 + nb] = c[r] + bia[nb];
        }
    }
    // zero the atomic-max accumulators (replaces two memset dispatches)
    const int gt = blockIdx.x * 256 + tid, gs = NBF * 256;
    for (int idx = gt; idx < NN * 64; idx += gs) y[idx] = 0u;
    for (int idx = gt; idx < NN * 8; idx += gs) y8[idx] = 0u;
}

// -------- fused BN apply + bf16 emit + NEXT layer's a0 GEMM + y re-zero ----

__global__ __launch_bounds__(256)
void bn_a0_64(unsigned* __restrict__ yk, const float* __restrict__ st,
              const float* __restrict__ g, const float* __restrict__ be,
              const float* __restrict__ w1n, const float* __restrict__ b1n,
              unsigned short* __restrict__ xbout, float* __restrict__ a0out) {
    __shared__ float sa[64], sb[64];
    const int tid = threadIdx.x;
    if (tid < 64) {
        float mu  = st[tid] * (1.0f / NN);
        float var = st[64 + tid] * (1.0f / NN) - mu * mu;
        float sc  = rsqrtf(var + 1e-5f) * g[tid];
        sa[tid] = sc;
        sb[tid] = be[tid] - mu * sc;
    }
    __syncthreads();
    const int lane = tid & 63;
    const int wid = blockIdx.x * 4 + (tid >> 6);
    const int i = lane & 15, q = lane >> 4;

    s8v wf[4][2];
#pragma unroll
    for (int nb = 0; nb < 4; nb++)
#pragma unroll
        for (int kh = 0; kh < 2; kh++)
#pragma unroll
            for (int j = 0; j < 8; j++) {
                int k = kh * 32 + q * 8 + j, n = nb * 16 + i;
                wf[nb][kh][j] = f2bf(w1n[k * 64 + n] - w1n[(64 + k) * 64 + n]);
            }
    float bia[4];
#pragma unroll
    for (int nb = 0; nb < 4; nb++) bia[nb] = b1n[nb * 16 + i];

    // per-lane norm constants for its 16 channels (k = kh*32 + q*8 + j)
    f4v a00 = *(const f4v*)(sa + q * 8),      a01 = *(const f4v*)(sa + q * 8 + 4);
    f4v a10 = *(const f4v*)(sa + 32 + q * 8), a11 = *(const f4v*)(sa + 36 + q * 8);
    f4v b00 = *(const f4v*)(sb + q * 8),      b01 = *(const f4v*)(sb + q * 8 + 4);
    f4v b10 = *(const f4v*)(sb + 32 + q * 8), b11 = *(const f4v*)(sb + 36 + q * 8);

    const uint4 z4 = {0u, 0u, 0u, 0u};
    for (int t = wid; t < NTN; t += NWF) {
        const int row = t * 16 + i;
        unsigned* yr = yk + (size_t)row * 64 + q * 8;
        uint4 u0 = *(const uint4*)yr,        u1 = *(const uint4*)(yr + 4);
        uint4 u2 = *(const uint4*)(yr + 32), u3 = *(const uint4*)(yr + 36);
        s8v af0, af1;
        af0[0] = f2bf(dec(u0.x) * a00[0] + b00[0]);
        af0[1] = f2bf(dec(u0.y) * a00[1] + b00[1]);
        af0[2] = f2bf(dec(u0.z) * a00[2] + b00[2]);
        af0[3] = f2bf(dec(u0.w) * a00[3] + b00[3]);
        af0[4] = f2bf(dec(u1.x) * a01[0] + b01[0]);
        af0[5] = f2bf(dec(u1.y) * a01[1] + b01[1]);
        af0[6] = f2bf(dec(u1.z) * a01[2] + b01[2]);
        af0[7] = f2bf(dec(u1.w) * a01[3] + b01[3]);
        af1[0] = f2bf(dec(u2.x) * a10[0] + b10[0]);
        af1[1] = f2bf(dec(u2.y) * a10[1] + b10[1]);
        af1[2] = f2bf(dec(u2.z) * a10[2] + b10[2]);
        af1[3] = f2bf(dec(u2.w) * a10[3] + b10[3]);
        af1[4] = f2bf(dec(u3.x) * a11[0] + b11[0]);
        af1[5] = f2bf(dec(u3.y) * a11[1] + b11[1]);
        af1[6] = f2bf(dec(u3.z) * a11[2] + b11[2]);
        af1[7] = f2bf(dec(u3.w) * a11[3] + b11[3]);

        unsigned short* xw = xbout + (size_t)row * 64 + q * 8;
        *(s8v*)xw = af0;
        *(s8v*)(xw + 32) = af1;
        *(uint4*)yr = z4;        *(uint4*)(yr + 4) = z4;    // re-zero for next layer
        *(uint4*)(yr + 32) = z4; *(uint4*)(yr + 36) = z4;

        const int rowq = t * 16 + q * 4;
#pragma unroll
        for (int nb = 0; nb < 4; nb++) {
            f4v c = {0.f, 0.f, 0.f, 0.f};
            c = MFMA16(af0, wf[nb][0], c);
            c = MFMA16(af1, wf[nb][1], c);
#pragma unroll
            for (int r = 0; r < 4; r++)
                a0out[(size_t)(rowq + r) * 64 + i * 4 + nb] = c[r] + bia[nb];
        }
    }
}

// variant for layer 2 -> 3: next layer dout = 8

__global__ __launch_bounds__(256)
void bn_a0_8(unsigned* __restrict__ yk, const float* __restrict__ st,
             const float* __restrict__ g, const float* __restrict__ be,
             const float* __restrict__ w1n, const float* __restrict__ b1n,
             unsigned short* __restrict__ xbout, float* __restrict__ a08) {
    __shared__ float sa[64], sb[64];
    const int tid = threadIdx.x;
    if (tid < 64) {
        float mu  = st[tid] * (1.0f / NN);
        float var = st[64 + tid] * (1.0f / NN) - mu * mu;
        float sc  = rsqrtf(var + 1e-5f) * g[tid];
        sa[tid] = sc;
        sb[tid] = be[tid] - mu * sc;
    }
    __syncthreads();
    const int lane = tid & 63;
    const int wid = blockIdx.x * 4 + (tid >> 6);
    const int i = lane & 15, q = lane >> 4;

    s8v wf[2];
#pragma unroll
    for (int kh = 0; kh < 2; kh++)
#pragma unroll
        for (int j = 0; j < 8; j++) {
            int k = kh * 32 + q * 8 + j;
            wf[kh][j] = (i < 8) ? f2bf(w1n[k * 8 + i] - w1n[(64 + k) * 8 + i]) : (short)0;
        }
    const float bia = (i < 8) ? b1n[i] : 0.0f;

    f4v a00 = *(const f4v*)(sa + q * 8),      a01 = *(const f4v*)(sa + q * 8 + 4);
    f4v a10 = *(const f4v*)(sa + 32 + q * 8), a11 = *(const f4v*)(sa + 36 + q * 8);
    f4v b00 = *(const f4v*)(sb + q * 8),      b01 = *(const f4v*)(sb + q * 8 + 4);
    f4v b10 = *(const f4v*)(sb + 32 + q * 8), b11 = *(const f4v*)(sb + 36 + q * 8);

    for (int t = wid; t < NTN; t += NWF) {
        const int row = t * 16 + i;
        const unsigned* yr = yk + (size_t)row * 64 + q * 8;
        uint4 u0 = *(const uint4*)yr,        u1 = *(const uint4*)(yr + 4);
        uint4 u2 = *(const uint4*)(yr + 32), u3 = *(const uint4*)(yr + 36);
        s8v af0, af1;
        af0[0] = f2bf(dec(u0.x) * a00[0] + b00[0]);
        af0[1] = f2bf(dec(u0.y) * a00[1] + b00[1]);
        af0[2] = f2bf(dec(u0.z) * a00[2] + b00[2]);
        af0[3] = f2bf(dec(u0.w) * a00[3] + b00[3]);
        af0[4] = f2bf(dec(u1.x) * a01[0] + b01[0]);
        af0[5] = f2bf(dec(u1.y) * a01[1] + b01[1]);
        af0[6] = f2bf(dec(u1.z) * a01[2] + b01[2]);
        af0[7] = f2bf(dec(u1.w) * a01[3] + b01[3]);
        af1[0] = f2bf(dec(u2.x) * a10[0] + b10[0]);
        af1[1] = f2bf(dec(u2.y) * a10[1] + b10[1]);
        af1[2] = f2bf(dec(u2.z) * a10[2] + b10[2]);
        af1[3] = f2bf(dec(u2.w) * a10[3] + b10[3]);
        af1[4] = f2bf(dec(u3.x) * a11[0] + b11[0]);
        af1[5] = f2bf(dec(u3.y) * a11[1] + b11[1]);
        af1[6] = f2bf(dec(u3.z) * a11[2] + b11[2]);
        af1[7] = f2bf(dec(u3.w) * a11[3] + b11[3]);

        unsigned short* xw = xbout + (size_t)row * 64 + q * 8;
        *(s8v*)xw = af0;
        *(s8v*)(xw + 32) = af1;

        f4v c = {0.f, 0.f, 0.f, 0.f};
        c = MFMA16(af0, wf[0], c);
        c = MFMA16(af1, wf[1], c);
        if (i < 8) {
            const int rowq = t * 16 + q * 4;
#pragma unroll
            for (int r = 0; r < 4; r++)
                a08[(size_t)(rowq + r) * 8 + i] = c[r] + bia;
        }
    }
}

// ------- edge-major fused MLP + segmented max, dout=64 -------
// (inner loop identical to R8-R11; balanced wave partition over 1536 blocks)

__global__ __launch_bounds__(256)
void edge_mfma64(const unsigned short* __restrict__ xb, const float* __restrict__ a0,
                 const float* __restrict__ w1, const float* __restrict__ w2,
                 const float* __restrict__ b2,
                 const int* __restrict__ csr_src, const int* __restrict__ csr_dst,
                 unsigned* __restrict__ y) {
    __shared__ float uld[4][16 * 68];                 // per-wave tile, stride 68
    __shared__ int dseg[4][2][20];                    // per-wave dst ids, dbuf
    __shared__ short w2l[8 * 64 * 8];                 // W2 frags: (nb*2+kh, lane, j)
    const int lane = threadIdx.x & 63;
    const int wv = threadIdx.x >> 6;
    const int wid = blockIdx.x * 4 + wv;
    const int i = lane & 15, q = lane >> 4;
    float* up = &uld[wv][0];

    // W1bot fragments stay register-resident (32 VGPRs)
    s8v w1f[4][2];
#pragma unroll
    for (int nb = 0; nb < 4; nb++)
#pragma unroll
        for (int kh = 0; kh < 2; kh++)
#pragma unroll
            for (int j = 0; j < 8; j++) {
                int k = kh * 32 + q * 8 + j, n = nb * 16 + i;
                w1f[nb][kh][j] = f2bf(w1[(64 + k) * 64 + n]);
            }
    // stage this wave's nb(=wv) W2 fragments into shared LDS
    {
        const int nb = wv;
#pragma unroll
        for (int kh = 0; kh < 2; kh++) {
            s8v uu;
#pragma unroll
            for (int j = 0; j < 8; j++) {
                int k = kh * 32 + q * 8 + j;
                uu[j] = f2bf(w2[k * 64 + nb * 16 + i]);
            }
            *(s8v*)(w2l + ((nb * 2 + kh) * 64 + lane) * 8) = uu;
        }
    }
    __syncthreads();

    const float b2c = b2[lane];                       // channel = lane (scan)

    // balanced partition: first R64 waves get B64+1 tiles, rest B64
    int t = wid * B64 + (wid < R64 ? wid : R64);
    const int tend = t + B64 + (wid < R64 ? 1 : 0);

    s8v af0_c, af1_c;
    {
        int s0 = csr_src[t * 16 + i];
        const unsigned short* xr = xb + (size_t)s0 * 64;
        af0_c = *(const s8v*)(xr + q * 8);
        af1_c = *(const s8v*)(xr + 32 + q * 8);
    }
    int src_n = (t + 1 < tend) ? csr_src[(t + 1) * 16 + i] : 0;
    if (lane < 17) {
        int e = t * 16 + lane;
        dseg[wv][t & 1][lane] = (e < EE) ? csr_dst[e] : -1;
    }
    asm volatile("s_waitcnt lgkmcnt(0)" ::: "memory");
    int dq_c[4];
#pragma unroll
    for (int r = 0; r < 4; r++) dq_c[r] = dseg[wv][t & 1][q * 4 + r];
    f4v a0r_c[4];
#pragma unroll
    for (int r = 0; r < 4; r++)
        a0r_c[r] = *(const f4v*)(a0 + (size_t)dq_c[r] * 64 + i * 4);

    float run = -INFINITY;                            // per-channel running max

    for (; t < tend; t++) {
        const bool has_n = (t + 1) < tend;
        int* dsg = &dseg[wv][t & 1][0];
        int* dsg_n = &dseg[wv][(t + 1) & 1][0];

        if (has_n && lane < 17) {
            int e = (t + 1) * 16 + lane;
            dsg_n[lane] = (e < EE) ? csr_dst[e] : -1;
        }
        s8v af0_n = {0,0,0,0,0,0,0,0}, af1_n = {0,0,0,0,0,0,0,0};
        if (has_n) {
            const unsigned short* xr = xb + (size_t)src_n * 64;
            af0_n = *(const s8v*)(xr + q * 8);
            af1_n = *(const s8v*)(xr + 32 + q * 8);
        }
        int src_nn = (t + 2 < tend) ? csr_src[(t + 2) * 16 + i] : 0;

        // GEMM1
        f4v c0 = {0.f, 0.f, 0.f, 0.f}, c1 = c0, c2 = c0, c3 = c0;
        c0 = MFMA16(af0_c, w1f[0][0], c0); c0 = MFMA16(af1_c, w1f[0][1], c0);
        c1 = MFMA16(af0_c, w1f[1][0], c1); c1 = MFMA16(af1_c, w1f[1][1], c1);
        c2 = MFMA16(af0_c, w1f[2][0], c2); c2 = MFMA16(af1_c, w1f[2][1], c2);
        c3 = MFMA16(af0_c, w1f[3][0], c3); c3 = MFMA16(af1_c, w1f[3][1], c3);

        asm volatile("" ::: "memory");
#pragma unroll
        for (int r = 0; r < 4; r++) {
            const int ro = (q * 4 + r) * 68 + i;
            up[ro +  0] = mish_fast(c0[r] + a0r_c[r][0]);
            up[ro + 16] = mish_fast(c1[r] + a0r_c[r][1]);
            up[ro + 32] = mish_fast(c2[r] + a0r_c[r][2]);
            up[ro + 48] = mish_fast(c3[r] + a0r_c[r][3]);
        }
        asm volatile("s_waitcnt lgkmcnt(0)" ::: "memory");   // wait#2

        int dq_n[4];
        f4v a0r_n[4];
        if (has_n) {
#pragma unroll
            for (int r = 0; r < 4; r++) dq_n[r] = dsg_n[q * 4 + r];
#pragma unroll
            for (int r = 0; r < 4; r++)
                a0r_n[r] = *(const f4v*)(a0 + (size_t)dq_n[r] * 64 + i * 4);
        }

        s8v uf[2];
#pragma unroll
        for (int kh = 0; kh < 2; kh++) {
            const f4v* rp = (const f4v*)(up + i * 68 + kh * 32 + q * 8);
            f4v v0 = rp[0], v1 = rp[1];
            s8v uu;
            uu[0] = f2bf(v0[0]); uu[1] = f2bf(v0[1]);
            uu[2] = f2bf(v0[2]); uu[3] = f2bf(v0[3]);
            uu[4] = f2bf(v1[0]); uu[5] = f2bf(v1[1]);
            uu[6] = f2bf(v1[2]); uu[7] = f2bf(v1[3]);
            uf[kh] = uu;
        }
        asm volatile("" ::: "memory");

        // GEMM2 (B fragments streamed from shared LDS)
        f4v cc[4];
#pragma unroll
        for (int nb = 0; nb < 4; nb++) {
            s8v b0 = *(const s8v*)(w2l + ((nb * 2 + 0) * 64 + lane) * 8);
            s8v b1v = *(const s8v*)(w2l + ((nb * 2 + 1) * 64 + lane) * 8);
            f4v c = {0.f, 0.f, 0.f, 0.f};
            c = MFMA16(uf[0], b0, c);
            c = MFMA16(uf[1], b1v, c);
            cc[nb] = c;
        }

#pragma unroll
        for (int nb = 0; nb < 4; nb++)
#pragma unroll
            for (int r = 0; r < 4; r++)
                up[(q * 4 + r) * 68 + nb * 16 + i] = cc[nb][r];
        asm volatile("s_waitcnt lgkmcnt(0)" ::: "memory");   // wait#3

        float v[16];
#pragma unroll
        for (int row = 0; row < 16; row++) v[row] = up[row * 68 + lane];

        int dcur = dsg[0];
#pragma unroll
        for (int row = 0; row < 16; row++) {
            run = fmaxf(run, v[row]);
            int dn = (row < 15) ? dsg[row + 1] : (has_n ? dsg[16] : -1);
            if (dcur != dn) {
                atomicMax(&y[(size_t)dcur * 64 + lane], enc(run + b2c));
                run = -INFINITY;
            }
            dcur = dn;
        }
        asm volatile("s_waitcnt lgkmcnt(0)" ::: "memory");  // WAR guard

        src_n = src_nn;
        af0_c = af0_n; af1_c = af1_n;
#pragma unroll
        for (int r = 0; r < 4; r++) a0r_c[r] = a0r_n[r];
    }
}

// ------- edge-major final layer, dout=8 (R9 verbatim: CHT chunking) ----

__global__ __launch_bounds__(256)
void edge_mfma16(const unsigned short* __restrict__ xb, const float* __restrict__ a0,
                 const float* __restrict__ w1, const float* __restrict__ w2,
                 const float* __restrict__ b2,
                 const int* __restrict__ csr_src, const int* __restrict__ csr_dst,
                 unsigned* __restrict__ y8) {
    __shared__ float uld[4][16 * 20];
    __shared__ int dseg[4][2][20];
    const int lane = threadIdx.x & 63;
    const int wv = threadIdx.x >> 6;
    const int wid = blockIdx.x * 4 + wv;
    const int i = lane & 15, q = lane >> 4;
    float* up = &uld[wv][0];

    s8v w1f[2], w2f;
#pragma unroll
    for (int kh = 0; kh < 2; kh++)
#pragma unroll
        for (int j = 0; j < 8; j++) {
            int k = kh * 32 + q * 8 + j;
            w1f[kh][j] = (i < 8) ? f2bf(w1[(64 + k) * 8 + i]) : (short)0;
        }
#pragma unroll
    for (int j = 0; j < 8; j++)
        w2f[j] = (q == 0 && i < 8) ? f2bf(w2[j * 8 + i]) : (short)0;
    const float b2c = (lane < 8) ? b2[lane] : 0.0f;

    int t = wid * CHT;
    if (t >= NT) return;
    const int tend = (t + CHT < NT) ? (t + CHT) : NT;

    s8v af0_c, af1_c;
    {
        int s0 = csr_src[t * 16 + i];
        const unsigned short* xr = xb + (size_t)s0 * 64;
        af0_c = *(const s8v*)(xr + q * 8);
        af1_c = *(const s8v*)(xr + 32 + q * 8);
    }
    int src_n = (t + 1 < tend) ? csr_src[(t + 1) * 16 + i] : 0;
    if (lane < 17) {
        int e = t * 16 + lane;
        dseg[wv][t & 1][lane] = (e < EE) ? csr_dst[e] : -1;
    }
    asm volatile("s_waitcnt lgkmcnt(0)" ::: "memory");
    int dq_c[4];
#pragma unroll
    for (int r = 0; r < 4; r++) dq_c[r] = dseg[wv][t & 1][q * 4 + r];
    float av_c[4];
#pragma unroll
    for (int r = 0; r < 4; r++)
        av_c[r] = (i < 8) ? a0[(size_t)dq_c[r] * 8 + i] : 0.0f;

    float run = -INFINITY;

    for (; t < tend; t++) {
        const bool has_n = (t + 1) < tend;
        int* dsg = &dseg[wv][t & 1][0];
        int* dsg_n = &dseg[wv][(t + 1) & 1][0];

        if (has_n && lane < 17) {
            int e = (t + 1) * 16 + lane;
            dsg_n[lane] = (e < EE) ? csr_dst[e] : -1;
        }
        s8v af0_n = {0,0,0,0,0,0,0,0}, af1_n = {0,0,0,0,0,0,0,0};
        if (has_n) {
            const unsigned short* xr = xb + (size_t)src_n * 64;
            af0_n = *(const s8v*)(xr + q * 8);
            af1_n = *(const s8v*)(xr + 32 + q * 8);
        }
        int src_nn = (t + 2 < tend) ? csr_src[(t + 2) * 16 + i] : 0;

        f4v c = {0.f, 0.f, 0.f, 0.f};
        c = MFMA16(af0_c, w1f[0], c);
        c = MFMA16(af1_c, w1f[1], c);

        asm volatile("" ::: "memory");
#pragma unroll
        for (int r = 0; r < 4; r++)
            up[(q * 4 + r) * 20 + i] = mish_fast(c[r] + av_c[r]);   // cols 8..15 = 0
        asm volatile("s_waitcnt lgkmcnt(0)" ::: "memory");           // wait#2

        int dq_n[4];
        float av_n[4] = {0, 0, 0, 0};
        if (has_n) {
#pragma unroll
            for (int r = 0; r < 4; r++) dq_n[r] = dsg_n[q * 4 + r];
#pragma unroll
            for (int r = 0; r < 4; r++)
                av_n[r] = (i < 8) ? a0[(size_t)dq_n[r] * 8 + i] : 0.0f;
        }

        s8v uf = {0,0,0,0,0,0,0,0};
        if (q < 2) {                                   // k = q*8+j < 16
            const f4v* rp = (const f4v*)(up + i * 20 + q * 8);
            f4v v0 = rp[0], v1 = rp[1];
            uf[0] = f2bf(v0[0]); uf[1] = f2bf(v0[1]);
            uf[2] = f2bf(v0[2]); uf[3] = f2bf(v0[3]);
            uf[4] = f2bf(v1[0]); uf[5] = f2bf(v1[1]);
            uf[6] = f2bf(v1[2]); uf[7] = f2bf(v1[3]);
        }
        asm volatile("" ::: "memory");

        f4v cc = {0.f, 0.f, 0.f, 0.f};
        cc = MFMA16(uf, w2f, cc);

#pragma unroll
        for (int r = 0; r < 4; r++)
            up[(q * 4 + r) * 20 + i] = cc[r];
        asm volatile("s_waitcnt lgkmcnt(0)" ::: "memory");           // wait#3

        float v[16];
#pragma unroll
        for (int row = 0; row < 16; row++) v[row] = up[row * 20 + (lane & 7)];

        int dcur = dsg[0];
#pragma unroll
        for (int row = 0; row < 16; row++) {
            run = fmaxf(run, v[row]);
            int dn = (row < 15) ? dsg[row + 1] : (has_n ? dsg[16] : -1);
            if (dcur != dn) {
                if (lane < 8)
                    atomicMax(&y8[(size_t)dcur * 8 + lane], enc(run + b2c));
                run = -INFINITY;
            }
            dcur = dn;
        }
        asm volatile("s_waitcnt lgkmcnt(0)" ::: "memory");

        src_n = src_nn;
        af0_c = af0_n; af1_c = af1_n;
#pragma unroll
        for (int r = 0; r < 4; r++) av_c[r] = av_n[r];
    }
}

// ---------------- BatchNorm stats (R9 verbatim: simple scalar) ----------------

__global__ __launch_bounds__(256)
void bn_stats(const unsigned* __restrict__ yk, float* __restrict__ st) {
    const int tid = threadIdx.x;
    const int ch = tid & 63, grp = tid >> 6;
    float s = 0, qq = 0;
    for (int n = blockIdx.x * 4 + grp; n < NN; n += gridDim.x * 4) {
        float v = dec(yk[(size_t)n * 64 + ch]);
        s += v;
        qq = fmaf(v, v, qq);
    }
    __shared__ float ls[256], lq[256];
    ls[tid] = s; lq[tid] = qq;
    __syncthreads();
    if (tid < 64) {
        s  = ls[tid] + ls[tid + 64] + ls[tid + 128] + ls[tid + 192];
        qq = lq[tid] + lq[tid + 64] + lq[tid + 128] + lq[tid + 192];
        atomicAdd(&st[ch], s);
        atomicAdd(&st[64 + ch], qq);
    }
}

__global__ __launch_bounds__(256)
void decode_out(const unsigned* __restrict__ y8, float* __restrict__ out) {
    int idx = blockIdx.x * 256 + threadIdx.x;
    if (idx < NN * 8) out[idx] = dec(y8[idx]);
}

// ---------------- launch ----------------

extern "C" void kernel_launch(void* const* d_in, const int* in_sizes, int n_in,
                              void* d_out, int out_size, void* d_ws, size_t ws_size,
                              hipStream_t stream) {
    const float* x0 = (const float*)d_in[0];
    const int*   ei = (const int*)d_in[1];
    const float* w1[4] = {(const float*)d_in[3],  (const float*)d_in[9],
                          (const float*)d_in[15], (const float*)d_in[21]};
    const float* b1[4] = {(const float*)d_in[4],  (const float*)d_in[10],
                          (const float*)d_in[16], (const float*)d_in[22]};
    const float* w2[4] = {(const float*)d_in[5],  (const float*)d_in[11],
                          (const float*)d_in[17], (const float*)d_in[23]};
    const float* b2[4] = {(const float*)d_in[6],  (const float*)d_in[12],
                          (const float*)d_in[18], (const float*)d_in[24]};
    const float* gg[3] = {(const float*)d_in[7],  (const float*)d_in[13],
                          (const float*)d_in[19]};
    const float* be[3] = {(const float*)d_in[8],  (const float*)d_in[14],
                          (const float*)d_in[20]};

    char* p = (char*)d_ws;
    auto alloc = [&](size_t bytes) -> char* {
        char* r = p;
        p += (bytes + 255) & ~(size_t)255;
        return r;
    };
    int*      cnt     = (int*)alloc((size_t)NN * 4);
    int*      part    = (int*)alloc((size_t)NBS * 4);
    int*      row_off = (int*)alloc((size_t)(NN + 1) * 4);
    int*      cur     = (int*)alloc((size_t)NN * 4);
    int*      csr_s   = (int*)alloc((size_t)EE * 4);
    int*      csr_d   = (int*)alloc((size_t)EE * 4);
    float*    st      = (float*)alloc(3 * 128 * 4);
    float*    a0      = (float*)alloc((size_t)NN * 64 * 4);   // reused for a0_8
    unsigned* y       = (unsigned*)alloc((size_t)NN * 64 * 4);
    unsigned* y8      = (unsigned*)alloc((size_t)NN * 8 * 4);
    unsigned short* xb0 = (unsigned short*)alloc((size_t)NN * 64 * 2);
    unsigned short* xbA = (unsigned short*)alloc((size_t)NN * 64 * 2);
    unsigned short* xbB = xb0;

    hipMemsetAsync(cnt, 0, (size_t)NN * 4, stream);
    hipMemsetAsync(st, 0, 3 * 128 * 4, stream);

    count_k<<<(EE + 255) / 256, 256, 0, stream>>>(ei, cnt);
    scan_part<<<NBS, 256, 0, stream>>>(cnt, part);
    scan_top<<<1, 256, 0, stream>>>(part);
    scan_fin<<<NBS, 256, 0, stream>>>(cnt, part, row_off, cur);
    scatter_k<<<(EE + 255) / 256, 256, 0, stream>>>(ei, cur, csr_s, csr_d);

    // layer 0 input prep: fp32->bf16 + a0 GEMM + zero y/y8
    cvt_a0<<<NBF, 256, 0, stream>>>(x0, w1[0], b1[0], xb0, a0, y, y8);

    // layer 0
    edge_mfma64<<<NBLK64, 256, 0, stream>>>(xb0, a0, w1[0], w2[0], b2[0],
                                            csr_s, csr_d, y);
    bn_stats<<<256, 256, 0, stream>>>(y, st);
    bn_a0_64<<<NBF, 256, 0, stream>>>(y, st, gg[0], be[0], w1[1], b1[1], xbA, a0);

    // layer 1
    edge_mfma64<<<NBLK64, 256, 0, stream>>>(xbA, a0, w1[1], w2[1], b2[1],
                                            csr_s, csr_d, y);
    bn_stats<<<256, 256, 0, stream>>>(y, st + 128);
    bn_a0_64<<<NBF, 256, 0, stream>>>(y, st + 128, gg[1], be[1], w1[2], b1[2], xbB, a0);

    // layer 2
    edge_mfma64<<<NBLK64, 256, 0, stream>>>(xbB, a0, w1[2], w2[2], b2[2],
                                            csr_s, csr_d, y);
    bn_stats<<<256, 256, 0, stream>>>(y, st + 256);
    bn_a0_8<<<NBF, 256, 0, stream>>>(y, st + 256, gg[2], be[2], w1[3], b1[3], xbA, a0);

    // layer 3: xbA -> d_out [N,8]
    edge_mfma16<<<NBLK, 256, 0, stream>>>(xbA, a0, w1[3], w2[3], b2[3],
                                          csr_s, csr_d, y8);
    decode_out<<<(NN * 8 + 255) / 256, 256, 0, stream>>>(y8, (float*)d_out);
}